// Round 1
// baseline (99704.919 us; speedup 1.0000x reference)
//
#include <hip/hip_runtime.h>
#include <math.h>

// ---------------------------------------------------------------------------
// FARGAN core. B=128, T=504, nb_frames=500, steps=2000, SUB=40.
// Round 1 design: fp32 everywhere, 1 block per batch row for the recurrence,
// weights pre-transposed (K x OUT) and streamed from L2.
// ---------------------------------------------------------------------------

#define DEV __device__ __forceinline__

DEV float sigm(float x) { return 1.0f / (1.0f + __expf(-x)); }
DEV float tanh_f(float x) { return 1.0f - 2.0f / (__expf(2.0f * x) + 1.0f); }

// ---- workspace layout (float offsets) ----
constexpr size_t NB = 128, NT = 504, NFR = 500, STEPS = 2000;
constexpr size_t OFF_COND = 0;                                   // 128*500*320 = 20,480,000
constexpr size_t OFF_Y    = 20480000;                            // 128*500*128 =  8,192,000
constexpr size_t OFF_GAIN = OFF_Y + 8192000;                     // 128*2000    =    256,000
constexpr size_t OFF_W    = OFF_GAIN + 256000;
// x-buffer (128*502*64 = 4,112,384) aliases the cond region (dead before cond written)
constexpr size_t OFF_X    = OFF_COND;

// transposed weight offsets (relative to OFF_W), layout: WT[k*OUT + j]
constexpr size_t W_FWC     = 0;                    // 328x192
constexpr size_t W_FWCGLU  = W_FWC + 328*192;      // 192x192
constexpr size_t W_GOUT    = W_FWCGLU + 192*192;   // 192x4
constexpr size_t W_G1IH    = W_GOUT + 192*4;       // 272x480
constexpr size_t W_G1HH    = W_G1IH + 272*480;     // 160x480
constexpr size_t W_GLU1    = W_G1HH + 160*480;     // 160x160
constexpr size_t W_G2IH    = W_GLU1 + 160*160;     // 240x384
constexpr size_t W_G2HH    = W_G2IH + 240*384;     // 128x384
constexpr size_t W_GLU2    = W_G2HH + 128*384;     // 128x128
constexpr size_t W_G3IH    = W_GLU2 + 128*128;     // 208x384
constexpr size_t W_G3HH    = W_G3IH + 208*384;     // 128x384
constexpr size_t W_GLU3    = W_G3HH + 128*384;     // 128x128
constexpr size_t W_SKIP    = W_GLU3 + 128*128;     // 688x128
constexpr size_t W_SKIPGLU = W_SKIP + 688*128;     // 128x128
constexpr size_t W_SIG     = W_SKIPGLU + 128*128;  // 128x40
constexpr size_t W_TOTAL   = W_SIG + 128*40;       // 746,240 floats

// ---------------------------------------------------------------------------
// transpose: dst[k*OUT + j] = src[j*K + k]
// ---------------------------------------------------------------------------
__global__ void k_transpose(const float* __restrict__ src, float* __restrict__ dst,
                            int OUT, int K) {
    int t = blockIdx.x * 256 + threadIdx.x;
    if (t >= OUT * K) return;
    int j = t % OUT;
    int k = t / OUT;
    dst[t] = src[j * K + k];
}

// ---------------------------------------------------------------------------
// frontend kernel 1: x = tanh([features[:,2:,:], pembed[pidx]] @ fd1_w.T)
// ---------------------------------------------------------------------------
__global__ void k_feat(const float* __restrict__ features, const int* __restrict__ period,
                       const float* __restrict__ pembed, const float* __restrict__ fd1,
                       float* __restrict__ xbuf) {
    int t = blockIdx.x * 256 + threadIdx.x;
    const int total = 128 * 502 * 64;
    if (t >= total) return;
    int o = t & 63;
    int r = t >> 6;
    int ft = r % 502;
    int b = r / 502;
    const float* f = features + ((size_t)b * 504 + ft + 2) * 20;
    int per = period[b * 504 + ft + 2];
    per = min(max(per, 32), 254);
    const float* pe = pembed + (per - 32) * 12;
    const float* w = fd1 + o * 32;
    float acc = 0.0f;
#pragma unroll
    for (int i = 0; i < 20; ++i) acc += f[i] * w[i];
#pragma unroll
    for (int i = 0; i < 12; ++i) acc += pe[i] * w[20 + i];
    xbuf[t] = tanh_f(acc);
}

// ---------------------------------------------------------------------------
// frontend kernel 2: y = tanh(conv1d(x^T, fconv1_w, VALID))^T   (cross-corr)
// ---------------------------------------------------------------------------
__global__ void k_conv(const float* __restrict__ xbuf, const float* __restrict__ fconv1,
                       float* __restrict__ ybuf) {
    int t = blockIdx.x * 256 + threadIdx.x;
    const int total = 128 * 500 * 128;
    if (t >= total) return;
    int oc = t & 127;
    int r = t >> 7;
    int tt = r % 500;
    int b = r / 500;
    const float* xp = xbuf + ((size_t)b * 502 + tt) * 64;
    const float* w = fconv1 + oc * 192;  // [oc][ic][tau], ic*3+tau
    float acc = 0.0f;
#pragma unroll 8
    for (int i = 0; i < 64; ++i) {
        acc += xp[i] * w[i * 3 + 0];
        acc += xp[64 + i] * w[i * 3 + 1];
        acc += xp[128 + i] * w[i * 3 + 2];
    }
    ybuf[t] = tanh_f(acc);
}

// ---------------------------------------------------------------------------
// frontend kernel 3: cond = tanh(y @ fd2_w.T). block: 320 threads, 10 frames.
// ---------------------------------------------------------------------------
__global__ void k_cond(const float* __restrict__ ybuf, const float* __restrict__ fd2,
                       float* __restrict__ cond) {
    int b = blockIdx.x / 50;
    int t0 = (blockIdx.x % 50) * 10;
    int tid = threadIdx.x;  // 0..319
    __shared__ float yl[1280];
    for (int i = tid; i < 1280; i += 320)
        yl[i] = ybuf[((size_t)b * 500 + t0) * 128 + i];
    __syncthreads();
    const float* w = fd2 + tid * 128;
    float acc[10];
#pragma unroll
    for (int q = 0; q < 10; ++q) acc[q] = 0.0f;
#pragma unroll 4
    for (int k = 0; k < 128; ++k) {
        float wv = w[k];
#pragma unroll
        for (int q = 0; q < 10; ++q) acc[q] += wv * yl[q * 128 + k];
    }
#pragma unroll
    for (int q = 0; q < 10; ++q)
        cond[((size_t)b * 500 + t0 + q) * 320 + tid] = tanh_f(acc[q]);
}

// ---------------------------------------------------------------------------
// frontend kernel 4: per-step gains
// ---------------------------------------------------------------------------
__global__ void k_gain(const float* __restrict__ cond, const float* __restrict__ cgw,
                       const float* __restrict__ cgb, float* __restrict__ gains) {
    int t = blockIdx.x * 256 + threadIdx.x;
    const int total = 128 * 2000;
    if (t >= total) return;
    int s = t % 2000;
    int b = t / 2000;
    int frame = s >> 2, sub = s & 3;
    const float* c = cond + ((size_t)b * 500 + frame) * 320 + sub * 80;
    float acc = 0.0f;
#pragma unroll 8
    for (int i = 0; i < 80; ++i) acc += c[i] * cgw[i];
    float g = 0.2f + 0.8f * sigm(acc + cgb[0]);
    g = fminf(20.0f, fmaxf(0.001f, g));
    gains[t] = g;
}

// ---------------------------------------------------------------------------
// matvec: dest[j] = dot(W[j,:], x) with WT laid out [k*OUT + j].
// S = K-split factor (requires K % S == 0, OUT*S <= 512). Trailing syncthreads.
// ---------------------------------------------------------------------------
template <int OUT, int K, int S>
DEV void matvec(const float* __restrict__ WT, const float* __restrict__ x,
                float* __restrict__ dest, float* __restrict__ scratch, int tid) {
    static_assert(K % S == 0, "K % S");
    static_assert(OUT * S <= 512, "threads");
    if (S == 1) {
        if (tid < OUT) {
            float acc = 0.0f;
            const float* w = WT + tid;
#pragma unroll 8
            for (int k = 0; k < K; ++k) acc += w[(size_t)k * OUT] * x[k];
            dest[tid] = acc;
        }
        __syncthreads();
    } else {
        constexpr int KS = K / S;
        if (tid < OUT * S) {
            int j = tid % OUT;
            int slice = tid / OUT;
            const float* w = WT + (size_t)slice * KS * OUT + j;
            const float* xx = x + slice * KS;
            float acc = 0.0f;
#pragma unroll 8
            for (int k = 0; k < KS; ++k) acc += w[(size_t)k * OUT] * xx[k];
            scratch[slice * OUT + j] = acc;
        }
        __syncthreads();
        if (tid < OUT) {
            float acc = 0.0f;
#pragma unroll
            for (int s2 = 0; s2 < S; ++s2) acc += scratch[s2 * OUT + tid];
            dest[tid] = acc;
        }
        __syncthreads();
    }
}

// GRU double matvec: gi[j] = dot(w1[j], x1); gh[j] = dot(w2[j], x2)
template <int OUT, int K1, int K2>
DEV void gru_mats(const float* __restrict__ w1T, const float* __restrict__ x1,
                  const float* __restrict__ w2T, const float* __restrict__ x2,
                  float* __restrict__ gi, float* __restrict__ gh, int tid) {
    if (tid < OUT) {
        float a1 = 0.0f, a2 = 0.0f;
        const float* w1 = w1T + tid;
        const float* w2 = w2T + tid;
#pragma unroll 8
        for (int k = 0; k < K1; ++k) a1 += w1[(size_t)k * OUT] * x1[k];
#pragma unroll 8
        for (int k = 0; k < K2; ++k) a2 += w2[(size_t)k * OUT] * x2[k];
        gi[tid] = a1;
        gh[tid] = a2;
    }
    __syncthreads();
}

// ---------------------------------------------------------------------------
// main recurrent kernel: 128 blocks (one per batch row) x 512 threads
// ---------------------------------------------------------------------------
__global__ __launch_bounds__(512) void fargan_main(const float* __restrict__ ws,
                                                   const int* __restrict__ period,
                                                   const float* __restrict__ goutb,
                                                   float* __restrict__ out) {
    const int b = blockIdx.x;
    const int tid = threadIdx.x;

    const float* cond  = ws + OFF_COND;
    const float* gains = ws + OFF_GAIN;
    const float* wb    = ws + OFF_W;
    const float* wFWC     = wb + W_FWC;
    const float* wFWCGLU  = wb + W_FWCGLU;
    const float* wGOUT    = wb + W_GOUT;
    const float* wG1IH    = wb + W_G1IH;
    const float* wG1HH    = wb + W_G1HH;
    const float* wGLU1    = wb + W_GLU1;
    const float* wG2IH    = wb + W_G2IH;
    const float* wG2HH    = wb + W_G2HH;
    const float* wGLU2    = wb + W_GLU2;
    const float* wG3IH    = wb + W_G3IH;
    const float* wG3HH    = wb + W_G3HH;
    const float* wGLU3    = wb + W_GLU3;
    const float* wSKIP    = wb + W_SKIP;
    const float* wSKIPGLU = wb + W_SKIPGLU;
    const float* wSIG     = wb + W_SIG;

    // xcat layout: [fwc_state 0..163 | cond80 164..243 | pred 244..287 | prev 288..327]
    __shared__ float xcat[328];
    __shared__ float exc[256];
    __shared__ float s1[160], s2[128], s3[128];
    __shared__ float gi[480], gh[480];
    __shared__ float scratch[512];
    __shared__ float fwcpre[192], glutmp[192], fwcout[192];
    __shared__ float goutraw[4], pg[4];
    __shared__ float inb[272];
    __shared__ float g1[160], g2[128], g3[128];
    __shared__ float skipin[688], skippre[128], skipout[128];
    __shared__ float sigraw[40];

    // zero-init state
    for (int i = tid; i < 256; i += 512) exc[i] = 0.0f;
    for (int i = tid; i < 160; i += 512) s1[i] = 0.0f;
    for (int i = tid; i < 128; i += 512) { s2[i] = 0.0f; s3[i] = 0.0f; }
    for (int i = tid; i < 164; i += 512) xcat[i] = 0.0f;
    __syncthreads();

    for (int s = 0; s < (int)STEPS; ++s) {
        const int frame = s >> 2;
        const float gain = gains[(size_t)b * 2000 + s];
        const float ig = 1.0f / (1e-5f + gain);
        int per = period[b * 504 + 3 + frame];
        per = min(max(per, 32), 254);

        // P1: gather cond80, pred, prev into xcat
        if (tid < 80) {
            xcat[164 + tid] = cond[((size_t)b * 500 + frame) * 320 + (s & 3) * 80 + tid];
        } else if (tid >= 128 && tid < 172) {
            int j = tid - 128;
            int idx = 254 - per + j;          // 256 - per + j - 2
            if (idx >= 256) idx -= per;
            idx = min(255, max(0, idx));
            xcat[244 + j] = exc[idx] * ig;
        } else if (tid >= 192 && tid < 232) {
            xcat[288 + tid - 192] = exc[216 + tid - 192] * ig;
        }
        __syncthreads();

        // fwc: tanh(xcat @ fwc_w.T), then GLU + gout
        matvec<192, 328, 2>(wFWC, xcat, fwcpre, scratch, tid);
        if (tid < 192) fwcpre[tid] = tanh_f(fwcpre[tid]);
        __syncthreads();
        matvec<192, 192, 2>(wFWCGLU, fwcpre, glutmp, scratch, tid);
        matvec<4, 192, 16>(wGOUT, fwcpre, goutraw, scratch, tid);
        if (tid < 192) {
            fwcout[tid] = fwcpre[tid] * sigm(glutmp[tid]);
        } else if (tid >= 448 && tid < 452) {
            pg[tid - 448] = sigm(goutraw[tid - 448] + goutb[tid - 448]);
        } else if (tid >= 256 && tid < 420) {
            // fwc_state' = tmp (shift xcat[164:328] into xcat[0:164])
            xcat[tid - 256] = xcat[tid - 256 + 164];
        }
        __syncthreads();

        // ---- GRU1 ----
        if (tid < 192) inb[tid] = fwcout[tid];
        else if (tid < 232) inb[tid] = pg[0] * xcat[246 + tid - 192];   // fpitch
        else if (tid < 272) inb[tid] = xcat[288 + tid - 232];           // prev
        __syncthreads();
        gru_mats<480, 272, 160>(wG1IH, inb, wG1HH, s1, gi, gh, tid);
        if (tid < 160) {
            float r = sigm(gi[tid] + gh[tid]);
            float z = sigm(gi[160 + tid] + gh[160 + tid]);
            float n = tanh_f(gi[320 + tid] + r * gh[320 + tid]);
            s1[tid] = (1.0f - z) * n + z * s1[tid];
        }
        __syncthreads();
        matvec<160, 160, 2>(wGLU1, s1, glutmp, scratch, tid);
        if (tid < 160) g1[tid] = s1[tid] * sigm(glutmp[tid]);
        __syncthreads();

        // ---- GRU2 ----
        if (tid < 160) inb[tid] = g1[tid];
        else if (tid < 200) inb[tid] = pg[1] * xcat[246 + tid - 160];
        else if (tid < 240) inb[tid] = xcat[288 + tid - 200];
        __syncthreads();
        gru_mats<384, 240, 128>(wG2IH, inb, wG2HH, s2, gi, gh, tid);
        if (tid < 128) {
            float r = sigm(gi[tid] + gh[tid]);
            float z = sigm(gi[128 + tid] + gh[128 + tid]);
            float n = tanh_f(gi[256 + tid] + r * gh[256 + tid]);
            s2[tid] = (1.0f - z) * n + z * s2[tid];
        }
        __syncthreads();
        matvec<128, 128, 4>(wGLU2, s2, glutmp, scratch, tid);
        if (tid < 128) g2[tid] = s2[tid] * sigm(glutmp[tid]);
        __syncthreads();

        // ---- GRU3 ----
        if (tid < 128) inb[tid] = g2[tid];
        else if (tid < 168) inb[tid] = pg[2] * xcat[246 + tid - 128];
        else if (tid < 208) inb[tid] = xcat[288 + tid - 168];
        __syncthreads();
        gru_mats<384, 208, 128>(wG3IH, inb, wG3HH, s3, gi, gh, tid);
        if (tid < 128) {
            float r = sigm(gi[tid] + gh[tid]);
            float z = sigm(gi[128 + tid] + gh[128 + tid]);
            float n = tanh_f(gi[256 + tid] + r * gh[256 + tid]);
            s3[tid] = (1.0f - z) * n + z * s3[tid];
        }
        __syncthreads();
        matvec<128, 128, 4>(wGLU3, s3, glutmp, scratch, tid);
        if (tid < 128) g3[tid] = s3[tid] * sigm(glutmp[tid]);
        __syncthreads();

        // ---- skip ----
        for (int i = tid; i < 688; i += 512) {
            float v;
            if (i < 160) v = g1[i];
            else if (i < 288) v = g2[i - 160];
            else if (i < 416) v = g3[i - 288];
            else if (i < 608) v = fwcout[i - 416];
            else if (i < 648) v = pg[3] * xcat[246 + i - 608];
            else v = xcat[288 + i - 648];
            skipin[i] = v;
        }
        __syncthreads();
        matvec<128, 688, 4>(wSKIP, skipin, skippre, scratch, tid);
        if (tid < 128) skippre[tid] = tanh_f(skippre[tid]);
        __syncthreads();
        matvec<128, 128, 4>(wSKIPGLU, skippre, glutmp, scratch, tid);
        if (tid < 128) skipout[tid] = skippre[tid] * sigm(glutmp[tid]);
        __syncthreads();

        // ---- sig + exc update + output ----
        matvec<40, 128, 8>(wSIG, skipout, sigraw, scratch, tid);
        float keep = (tid < 216) ? exc[tid + 40] : 0.0f;
        float sv = 0.0f;
        if (tid >= 216 && tid < 256) sv = tanh_f(sigraw[tid - 216]) * gain;
        __syncthreads();
        if (tid < 216) {
            exc[tid] = keep;
        } else if (tid < 256) {
            exc[tid] = sv;
            out[(size_t)b * 80000 + (size_t)s * 40 + (tid - 216)] = sv;
        }
        __syncthreads();
    }
}

// ---------------------------------------------------------------------------
extern "C" void kernel_launch(void* const* d_in, const int* in_sizes, int n_in,
                              void* d_out, int out_size, void* d_ws, size_t ws_size,
                              hipStream_t stream) {
    const float* features = (const float*)d_in[0];
    const int*   period   = (const int*)d_in[1];
    const float* pembed   = (const float*)d_in[2];
    const float* fd1_w    = (const float*)d_in[3];
    const float* fconv1_w = (const float*)d_in[4];
    const float* fd2_w    = (const float*)d_in[5];
    const float* cg_w     = (const float*)d_in[6];
    const float* cg_b     = (const float*)d_in[7];
    const float* fwc_w    = (const float*)d_in[8];
    const float* fwc_glu  = (const float*)d_in[9];
    const float* g1_ih    = (const float*)d_in[10];
    const float* g1_hh    = (const float*)d_in[11];
    const float* glu1_w   = (const float*)d_in[12];
    const float* g2_ih    = (const float*)d_in[13];
    const float* g2_hh    = (const float*)d_in[14];
    const float* glu2_w   = (const float*)d_in[15];
    const float* g3_ih    = (const float*)d_in[16];
    const float* g3_hh    = (const float*)d_in[17];
    const float* glu3_w   = (const float*)d_in[18];
    const float* skip_w   = (const float*)d_in[19];
    const float* skip_glu = (const float*)d_in[20];
    const float* sig_w    = (const float*)d_in[21];
    const float* gout_w   = (const float*)d_in[22];
    const float* gout_b   = (const float*)d_in[23];

    float* ws = (float*)d_ws;
    float* out = (float*)d_out;

    // ---- transpose all recurrent weights into ws ----
    struct TW { const float* src; size_t off; int out, k; };
    const TW tws[15] = {
        {fwc_w,    W_FWC,     192, 328}, {fwc_glu, W_FWCGLU, 192, 192},
        {gout_w,   W_GOUT,      4, 192}, {g1_ih,   W_G1IH,   480, 272},
        {g1_hh,    W_G1HH,    480, 160}, {glu1_w,  W_GLU1,   160, 160},
        {g2_ih,    W_G2IH,    384, 240}, {g2_hh,   W_G2HH,   384, 128},
        {glu2_w,   W_GLU2,    128, 128}, {g3_ih,   W_G3IH,   384, 208},
        {g3_hh,    W_G3HH,    384, 128}, {glu3_w,  W_GLU3,   128, 128},
        {skip_w,   W_SKIP,    128, 688}, {skip_glu,W_SKIPGLU,128, 128},
        {sig_w,    W_SIG,      40, 128},
    };
    for (int i = 0; i < 15; ++i) {
        int n = tws[i].out * tws[i].k;
        k_transpose<<<(n + 255) / 256, 256, 0, stream>>>(tws[i].src, ws + OFF_W + tws[i].off,
                                                         tws[i].out, tws[i].k);
    }

    // ---- frontend ----
    {
        int n = 128 * 502 * 64;
        k_feat<<<(n + 255) / 256, 256, 0, stream>>>(features, period, pembed, fd1_w,
                                                    ws + OFF_X);
    }
    {
        int n = 128 * 500 * 128;
        k_conv<<<(n + 255) / 256, 256, 0, stream>>>(ws + OFF_X, fconv1_w, ws + OFF_Y);
    }
    k_cond<<<128 * 50, 320, 0, stream>>>(ws + OFF_Y, fd2_w, ws + OFF_COND);
    {
        int n = 128 * 2000;
        k_gain<<<(n + 255) / 256, 256, 0, stream>>>(ws + OFF_COND, cg_w, cg_b,
                                                    ws + OFF_GAIN);
    }

    // ---- recurrence ----
    fargan_main<<<128, 512, 0, stream>>>(ws, period, gout_b, out);
}

// Round 2
// 62352.930 us; speedup vs baseline: 1.5990x; 1.5990x over previous
//
#include <hip/hip_runtime.h>
#include <math.h>

// ---------------------------------------------------------------------------
// FARGAN core. B=128, T=504, nb_frames=500, steps=2000, SUB=40.
// Round 2: float4-packed weights ([k/4][OUT] layout, 16B/lane coalesced),
// 1024 threads/block (16 waves), fused phases (~24 barriers/step).
// ---------------------------------------------------------------------------

#define DEV __device__ __forceinline__

DEV float sigm(float x) { return 1.0f / (1.0f + __expf(-x)); }
DEV float tanh_f(float x) { return 1.0f - 2.0f / (__expf(2.0f * x) + 1.0f); }

// ---- workspace layout (float offsets) ----
constexpr size_t STEPS = 2000;
constexpr size_t OFF_COND = 0;                                   // 128*500*320
constexpr size_t OFF_Y    = 20480000;                            // 128*500*128
constexpr size_t OFF_GAIN = OFF_Y + 8192000;                     // 128*2000
constexpr size_t OFF_W    = OFF_GAIN + 256000;                   // mult of 4
constexpr size_t OFF_X    = OFF_COND;                            // aliases cond (dead)

// packed weight sizes: OUT * KPAD floats, layout float4[(k/4)*OUT + j]
constexpr size_t W_FWC     = 0;                      // 192 x 336
constexpr size_t W_FWCGLU  = W_FWC    + 192*336;     // 192 x 192
constexpr size_t W_GOUT    = W_FWCGLU + 192*192;     // 4   x 192
constexpr size_t W_G1IH    = W_GOUT   + 4*192;       // 480 x 272
constexpr size_t W_G1HH    = W_G1IH   + 480*272;     // 480 x 160
constexpr size_t W_GLU1    = W_G1HH   + 480*160;     // 160 x 160
constexpr size_t W_G2IH    = W_GLU1   + 160*160;     // 384 x 240
constexpr size_t W_G2HH    = W_G2IH   + 384*240;     // 384 x 128
constexpr size_t W_GLU2    = W_G2HH   + 384*128;     // 128 x 128
constexpr size_t W_G3IH    = W_GLU2   + 128*128;     // 384 x 208
constexpr size_t W_G3HH    = W_G3IH   + 384*208;     // 384 x 128
constexpr size_t W_GLU3    = W_G3HH   + 384*128;     // 128 x 128
constexpr size_t W_SKIP    = W_GLU3   + 128*128;     // 128 x 704
constexpr size_t W_SKIPGLU = W_SKIP   + 128*704;     // 128 x 128
constexpr size_t W_SIG     = W_SKIPGLU+ 128*128;     // 40  x 128

// ---------------------------------------------------------------------------
// pack: dst4[(k/4)*OUT + j] = {W[j][4k..4k+3]} with zero pad past K
// ---------------------------------------------------------------------------
__global__ void k_pack(const float* __restrict__ src, float4* __restrict__ dst,
                       int OUT, int K, int KP4) {
    int t = blockIdx.x * 256 + threadIdx.x;
    if (t >= OUT * KP4) return;
    int j = t % OUT;
    int k4 = t / OUT;
    int k = k4 * 4;
    float4 v;
    v.x = (k     < K) ? src[(size_t)j * K + k    ] : 0.0f;
    v.y = (k + 1 < K) ? src[(size_t)j * K + k + 1] : 0.0f;
    v.z = (k + 2 < K) ? src[(size_t)j * K + k + 2] : 0.0f;
    v.w = (k + 3 < K) ? src[(size_t)j * K + k + 3] : 0.0f;
    dst[t] = v;
}

// ---------------------------------------------------------------------------
// frontend (unchanged from round 1 — verified correct)
// ---------------------------------------------------------------------------
__global__ void k_feat(const float* __restrict__ features, const int* __restrict__ period,
                       const float* __restrict__ pembed, const float* __restrict__ fd1,
                       float* __restrict__ xbuf) {
    int t = blockIdx.x * 256 + threadIdx.x;
    const int total = 128 * 502 * 64;
    if (t >= total) return;
    int o = t & 63;
    int r = t >> 6;
    int ft = r % 502;
    int b = r / 502;
    const float* f = features + ((size_t)b * 504 + ft + 2) * 20;
    int per = period[b * 504 + ft + 2];
    per = min(max(per, 32), 254);
    const float* pe = pembed + (per - 32) * 12;
    const float* w = fd1 + o * 32;
    float acc = 0.0f;
#pragma unroll
    for (int i = 0; i < 20; ++i) acc += f[i] * w[i];
#pragma unroll
    for (int i = 0; i < 12; ++i) acc += pe[i] * w[20 + i];
    xbuf[t] = tanh_f(acc);
}

__global__ void k_conv(const float* __restrict__ xbuf, const float* __restrict__ fconv1,
                       float* __restrict__ ybuf) {
    int t = blockIdx.x * 256 + threadIdx.x;
    const int total = 128 * 500 * 128;
    if (t >= total) return;
    int oc = t & 127;
    int r = t >> 7;
    int tt = r % 500;
    int b = r / 500;
    const float* xp = xbuf + ((size_t)b * 502 + tt) * 64;
    const float* w = fconv1 + oc * 192;
    float acc = 0.0f;
#pragma unroll 8
    for (int i = 0; i < 64; ++i) {
        acc += xp[i] * w[i * 3 + 0];
        acc += xp[64 + i] * w[i * 3 + 1];
        acc += xp[128 + i] * w[i * 3 + 2];
    }
    ybuf[t] = tanh_f(acc);
}

__global__ void k_cond(const float* __restrict__ ybuf, const float* __restrict__ fd2,
                       float* __restrict__ cond) {
    int b = blockIdx.x / 50;
    int t0 = (blockIdx.x % 50) * 10;
    int tid = threadIdx.x;
    __shared__ float yl[1280];
    for (int i = tid; i < 1280; i += 320)
        yl[i] = ybuf[((size_t)b * 500 + t0) * 128 + i];
    __syncthreads();
    const float* w = fd2 + tid * 128;
    float acc[10];
#pragma unroll
    for (int q = 0; q < 10; ++q) acc[q] = 0.0f;
#pragma unroll 4
    for (int k = 0; k < 128; ++k) {
        float wv = w[k];
#pragma unroll
        for (int q = 0; q < 10; ++q) acc[q] += wv * yl[q * 128 + k];
    }
#pragma unroll
    for (int q = 0; q < 10; ++q)
        cond[((size_t)b * 500 + t0 + q) * 320 + tid] = tanh_f(acc[q]);
}

__global__ void k_gain(const float* __restrict__ cond, const float* __restrict__ cgw,
                       const float* __restrict__ cgb, float* __restrict__ gains) {
    int t = blockIdx.x * 256 + threadIdx.x;
    const int total = 128 * 2000;
    if (t >= total) return;
    int s = t % 2000;
    int b = t / 2000;
    int frame = s >> 2, sub = s & 3;
    const float* c = cond + ((size_t)b * 500 + frame) * 320 + sub * 80;
    float acc = 0.0f;
#pragma unroll 8
    for (int i = 0; i < 80; ++i) acc += c[i] * cgw[i];
    float g = 0.2f + 0.8f * sigm(acc + cgb[0]);
    g = fminf(20.0f, fmaxf(0.001f, g));
    gains[t] = g;
}

// ---------------------------------------------------------------------------
// packed-matvec partial: part[sl*OUT + j] = dot(W[j, sl-slice], x[sl-slice])
// WT4 layout: float4[(k/4)*OUT + j]. KP4 = KPAD/4, S slices of KS4 each.
// NO trailing barrier.
// ---------------------------------------------------------------------------
template <int OUT, int KP4, int S>
DEV void mv_partial(const float4* __restrict__ WT, const float* __restrict__ x,
                    float* __restrict__ part, int tid) {
    static_assert(KP4 % S == 0, "KP4 % S");
    static_assert(OUT * S <= 1024, "threads");
    constexpr int KS4 = KP4 / S;
    if (tid < OUT * S) {
        int j = tid % OUT;
        int sl = tid / OUT;
        const float4* w = WT + (size_t)sl * KS4 * OUT + j;
        const float4* xx = (const float4*)x + sl * KS4;
        float a0 = 0.0f, a1 = 0.0f;
#pragma unroll 4
        for (int k = 0; k < KS4; ++k) {
            float4 wv = w[(size_t)k * OUT];
            float4 xv = xx[k];
            a0 += wv.x * xv.x;
            a1 += wv.y * xv.y;
            a0 += wv.z * xv.z;
            a1 += wv.w * xv.w;
        }
        part[tid] = a0 + a1;
    }
}

// GRU double partial, S=2 fixed: pa/pb get gi/gh partials
template <int OUT, int KP4A, int KP4B>
DEV void gru_partial(const float4* __restrict__ wa, const float* __restrict__ xa,
                     const float4* __restrict__ wb, const float* __restrict__ xb,
                     float* __restrict__ pa, float* __restrict__ pb, int tid) {
    static_assert((KP4A % 2 == 0) && (KP4B % 2 == 0), "even");
    constexpr int KA = KP4A / 2, KB = KP4B / 2;
    if (tid < OUT * 2) {
        int j = tid % OUT;
        int sl = tid / OUT;
        {
            const float4* w = wa + (size_t)sl * KA * OUT + j;
            const float4* xx = (const float4*)xa + sl * KA;
            float a0 = 0.0f, a1 = 0.0f;
#pragma unroll 4
            for (int k = 0; k < KA; ++k) {
                float4 wv = w[(size_t)k * OUT];
                float4 xv = xx[k];
                a0 += wv.x * xv.x; a1 += wv.y * xv.y;
                a0 += wv.z * xv.z; a1 += wv.w * xv.w;
            }
            pa[tid] = a0 + a1;
        }
        {
            const float4* w = wb + (size_t)sl * KB * OUT + j;
            const float4* xx = (const float4*)xb + sl * KB;
            float b0 = 0.0f, b1 = 0.0f;
#pragma unroll 4
            for (int k = 0; k < KB; ++k) {
                float4 wv = w[(size_t)k * OUT];
                float4 xv = xx[k];
                b0 += wv.x * xv.x; b1 += wv.y * xv.y;
                b0 += wv.z * xv.z; b1 += wv.w * xv.w;
            }
            pb[tid] = b0 + b1;
        }
    }
}

// GRU state update from partials (OUT = 3H, S = 2)
template <int H>
DEV void gru_update(const float* __restrict__ pa, const float* __restrict__ pb,
                    float* __restrict__ s, int tid) {
    constexpr int OUT = 3 * H;
    if (tid < H) {
        float gi_r = pa[tid] + pa[OUT + tid];
        float gh_r = pb[tid] + pb[OUT + tid];
        float gi_z = pa[H + tid] + pa[OUT + H + tid];
        float gh_z = pb[H + tid] + pb[OUT + H + tid];
        float gi_n = pa[2 * H + tid] + pa[OUT + 2 * H + tid];
        float gh_n = pb[2 * H + tid] + pb[OUT + 2 * H + tid];
        float r = sigm(gi_r + gh_r);
        float z = sigm(gi_z + gh_z);
        float n = tanh_f(gi_n + r * gh_n);
        s[tid] = (1.0f - z) * n + z * s[tid];
    }
}

// ---------------------------------------------------------------------------
// main recurrent kernel: 128 blocks x 1024 threads
// ---------------------------------------------------------------------------
__global__ __launch_bounds__(1024) void fargan_main(const float* __restrict__ ws,
                                                    const int* __restrict__ period,
                                                    const float* __restrict__ goutb,
                                                    float* __restrict__ out) {
    const int b = blockIdx.x;
    const int tid = threadIdx.x;

    const float* cond  = ws + OFF_COND;
    const float* gains = ws + OFF_GAIN;
    const float* wb    = ws + OFF_W;
    const float4* wFWC     = (const float4*)(wb + W_FWC);
    const float4* wFWCGLU  = (const float4*)(wb + W_FWCGLU);
    const float4* wGOUT    = (const float4*)(wb + W_GOUT);
    const float4* wG1IH    = (const float4*)(wb + W_G1IH);
    const float4* wG1HH    = (const float4*)(wb + W_G1HH);
    const float4* wGLU1    = (const float4*)(wb + W_GLU1);
    const float4* wG2IH    = (const float4*)(wb + W_G2IH);
    const float4* wG2HH    = (const float4*)(wb + W_G2HH);
    const float4* wGLU2    = (const float4*)(wb + W_GLU2);
    const float4* wG3IH    = (const float4*)(wb + W_G3IH);
    const float4* wG3HH    = (const float4*)(wb + W_G3HH);
    const float4* wGLU3    = (const float4*)(wb + W_GLU3);
    const float4* wSKIP    = (const float4*)(wb + W_SKIP);
    const float4* wSKIPGLU = (const float4*)(wb + W_SKIPGLU);
    const float4* wSIG     = (const float4*)(wb + W_SIG);

    // xcat: [fwc_state 0..163 | cond80 164..243 | pred 244..287 | prev 288..327 | pad..335]
    __shared__ __align__(16) float xcat[336];
    __shared__ __align__(16) float exc[256];
    __shared__ __align__(16) float s1[160], s2[128], s3[128];
    __shared__ __align__(16) float partA[1024], partB[1024];
    __shared__ __align__(16) float fwcpre[192], fwcout[192];
    __shared__ __align__(16) float pg[4];
    __shared__ __align__(16) float inb[272];
    __shared__ __align__(16) float g1[160], g2[128], g3[128];
    __shared__ __align__(16) float skipin[704], skippre[128], skipout[128];
    __shared__ __align__(16) float sigraw[40];

    // zero-init
    for (int i = tid; i < 256; i += 1024) exc[i] = 0.0f;
    if (tid < 160) s1[tid] = 0.0f;
    if (tid < 128) { s2[tid] = 0.0f; s3[tid] = 0.0f; }
    if (tid < 164) xcat[tid] = 0.0f;
    if (tid >= 328 && tid < 336) xcat[tid] = 0.0f;          // fwc K-pad
    if (tid >= 688 && tid < 704) skipin[tid] = 0.0f;        // skip K-pad
    __syncthreads();

    for (int s = 0; s < (int)STEPS; ++s) {
        const int frame = s >> 2;
        const float gain = gains[(size_t)b * 2000 + s];
        const float ig = 1.0f / (1e-5f + gain);
        int per = period[b * 504 + 3 + frame];
        per = min(max(per, 32), 254);

        // Phase A: gather cond80, pred, prev into xcat
        if (tid < 80) {
            xcat[164 + tid] = cond[((size_t)b * 500 + frame) * 320 + (s & 3) * 80 + tid];
        } else if (tid >= 128 && tid < 172) {
            int j = tid - 128;
            int idx = 254 - per + j;
            if (idx >= 256) idx -= per;
            idx = min(255, max(0, idx));
            xcat[244 + j] = exc[idx] * ig;
        } else if (tid >= 192 && tid < 232) {
            xcat[288 + tid - 192] = exc[216 + tid - 192] * ig;
        }
        __syncthreads();

        // Phase B: fwc partial (OUT=192, KPAD=336 -> KP4=84, S=4)
        mv_partial<192, 84, 4>(wFWC, xcat, partA, tid);
        __syncthreads();
        // Phase C: reduce -> fwcpre = tanh
        if (tid < 192) {
            float a = partA[tid] + partA[192 + tid] + partA[384 + tid] + partA[576 + tid];
            fwcpre[tid] = tanh_f(a);
        }
        __syncthreads();

        // Phase D: fwcglu partial (768 thr) || gout partial (64 thr) || xcat shift
        mv_partial<192, 48, 4>(wFWCGLU, fwcpre, partA, tid);
        if (tid >= 768 && tid < 832) {
            int t2 = tid - 768;
            int j = t2 & 3, sl = t2 >> 2;           // OUT=4, KP4=48, S=16 -> KS4=3
            const float4* w = wGOUT + sl * 3 * 4 + j;
            const float4* xx = (const float4*)fwcpre + sl * 3;
            float a = 0.0f;
#pragma unroll
            for (int k = 0; k < 3; ++k) {
                float4 wv = w[k * 4];
                float4 xv = xx[k];
                a += wv.x * xv.x + wv.y * xv.y + wv.z * xv.z + wv.w * xv.w;
            }
            partB[t2] = a;
        } else if (tid >= 832 && tid < 996) {
            xcat[tid - 832] = xcat[tid - 832 + 164];   // fwc_state' shift
        }
        __syncthreads();

        // Phase E: fwcout + pg + inb(gru1) build
        if (tid < 192) {
            float a = partA[tid] + partA[192 + tid] + partA[384 + tid] + partA[576 + tid];
            float v = fwcpre[tid] * sigm(a);
            fwcout[tid] = v;
            inb[tid] = v;
        } else if (tid < 232) {
            // redundant pg0 recompute breaks cross-thread dependency in-phase
            float a = goutb[0];
#pragma unroll
            for (int sl = 0; sl < 16; ++sl) a += partB[sl * 4];
            inb[tid] = sigm(a) * xcat[246 + tid - 192];
        } else if (tid < 272) {
            inb[tid] = xcat[288 + tid - 232];
        } else if (tid >= 960 && tid < 964) {
            int j = tid - 960;
            float a = goutb[j];
#pragma unroll
            for (int sl = 0; sl < 16; ++sl) a += partB[sl * 4 + j];
            pg[j] = sigm(a);
        }
        __syncthreads();

        // Phase F/G: GRU1 (H=160, OUT=480; K 272/160 -> KP4 68/40)
        gru_partial<480, 68, 40>(wG1IH, inb, wG1HH, s1, partA, partB, tid);
        __syncthreads();
        gru_update<160>(partA, partB, s1, tid);
        __syncthreads();

        // Phase H/I: GLU1 (160x160, KP4=40, S=4) + inb(gru2) build
        mv_partial<160, 40, 4>(wGLU1, s1, partA, tid);
        __syncthreads();
        if (tid < 160) {
            float a = partA[tid] + partA[160 + tid] + partA[320 + tid] + partA[480 + tid];
            float v = s1[tid] * sigm(a);
            g1[tid] = v;
            inb[tid] = v;
        } else if (tid < 200) {
            inb[tid] = pg[1] * xcat[246 + tid - 160];
        } else if (tid < 240) {
            inb[tid] = xcat[288 + tid - 200];
        }
        __syncthreads();

        // Phase J/K: GRU2 (H=128, OUT=384; K 240/128 -> KP4 60/32)
        gru_partial<384, 60, 32>(wG2IH, inb, wG2HH, s2, partA, partB, tid);
        __syncthreads();
        gru_update<128>(partA, partB, s2, tid);
        __syncthreads();

        // Phase L/M: GLU2 (128x128, KP4=32, S=8) + inb(gru3) build
        mv_partial<128, 32, 8>(wGLU2, s2, partA, tid);
        __syncthreads();
        if (tid < 128) {
            float a = 0.0f;
#pragma unroll
            for (int sl = 0; sl < 8; ++sl) a += partA[sl * 128 + tid];
            float v = s2[tid] * sigm(a);
            g2[tid] = v;
            inb[tid] = v;
        } else if (tid < 168) {
            inb[tid] = pg[2] * xcat[246 + tid - 128];
        } else if (tid < 208) {
            inb[tid] = xcat[288 + tid - 168];
        }
        __syncthreads();

        // Phase N/O: GRU3 (H=128, OUT=384; K 208/128 -> KP4 52/32)
        gru_partial<384, 52, 32>(wG3IH, inb, wG3HH, s3, partA, partB, tid);
        __syncthreads();
        gru_update<128>(partA, partB, s3, tid);
        __syncthreads();

        // Phase P/Q: GLU3 + skipin build
        mv_partial<128, 32, 8>(wGLU3, s3, partA, tid);
        __syncthreads();
        // skipin: [g1 0..159 | g2 160..287 | g3 288..415 | fwcout 416..607 | pitch 608..647 | prev 648..687]
        if (tid < 128) {
            float a = 0.0f;
#pragma unroll
            for (int sl = 0; sl < 8; ++sl) a += partA[sl * 128 + tid];
            float v = s3[tid] * sigm(a);
            g3[tid] = v;
            skipin[288 + tid] = v;
        } else if (tid < 288) {
            skipin[tid - 128] = g1[tid - 128];
        } else if (tid < 416) {
            skipin[160 + tid - 288] = g2[tid - 288];
        } else if (tid < 608) {
            skipin[416 + tid - 416] = fwcout[tid - 416];
        } else if (tid < 648) {
            skipin[tid] = pg[3] * xcat[246 + tid - 608];
        } else if (tid < 688) {
            skipin[tid] = xcat[288 + tid - 648];
        }
        __syncthreads();

        // Phase R/S: skip (128x688, KPAD=704 -> KP4=176, S=8)
        mv_partial<128, 176, 8>(wSKIP, skipin, partA, tid);
        __syncthreads();
        if (tid < 128) {
            float a = 0.0f;
#pragma unroll
            for (int sl = 0; sl < 8; ++sl) a += partA[sl * 128 + tid];
            skippre[tid] = tanh_f(a);
        }
        __syncthreads();

        // Phase T/U: skipglu (128x128)
        mv_partial<128, 32, 8>(wSKIPGLU, skippre, partA, tid);
        __syncthreads();
        if (tid < 128) {
            float a = 0.0f;
#pragma unroll
            for (int sl = 0; sl < 8; ++sl) a += partA[sl * 128 + tid];
            skipout[tid] = skippre[tid] * sigm(a);
        }
        __syncthreads();

        // Phase V: sig partial (40x128, KP4=32, S=8)
        mv_partial<40, 32, 8>(wSIG, skipout, partA, tid);
        __syncthreads();
        // Phase W: sig reduce + read old exc
        float keep = (tid < 216) ? exc[tid + 40] : 0.0f;
        if (tid < 40) {
            float a = 0.0f;
#pragma unroll
            for (int sl = 0; sl < 8; ++sl) a += partA[sl * 40 + tid];
            sigraw[tid] = tanh_f(a) * gain;
        }
        __syncthreads();
        // Phase X: exc shift + output
        if (tid < 216) {
            exc[tid] = keep;
        } else if (tid < 256) {
            float sv = sigraw[tid - 216];
            exc[tid] = sv;
            out[(size_t)b * 80000 + (size_t)s * 40 + (tid - 216)] = sv;
        }
        __syncthreads();
    }
}

// ---------------------------------------------------------------------------
extern "C" void kernel_launch(void* const* d_in, const int* in_sizes, int n_in,
                              void* d_out, int out_size, void* d_ws, size_t ws_size,
                              hipStream_t stream) {
    const float* features = (const float*)d_in[0];
    const int*   period   = (const int*)d_in[1];
    const float* pembed   = (const float*)d_in[2];
    const float* fd1_w    = (const float*)d_in[3];
    const float* fconv1_w = (const float*)d_in[4];
    const float* fd2_w    = (const float*)d_in[5];
    const float* cg_w     = (const float*)d_in[6];
    const float* cg_b     = (const float*)d_in[7];
    const float* fwc_w    = (const float*)d_in[8];
    const float* fwc_glu  = (const float*)d_in[9];
    const float* g1_ih    = (const float*)d_in[10];
    const float* g1_hh    = (const float*)d_in[11];
    const float* glu1_w   = (const float*)d_in[12];
    const float* g2_ih    = (const float*)d_in[13];
    const float* g2_hh    = (const float*)d_in[14];
    const float* glu2_w   = (const float*)d_in[15];
    const float* g3_ih    = (const float*)d_in[16];
    const float* g3_hh    = (const float*)d_in[17];
    const float* glu3_w   = (const float*)d_in[18];
    const float* skip_w   = (const float*)d_in[19];
    const float* skip_glu = (const float*)d_in[20];
    const float* sig_w    = (const float*)d_in[21];
    const float* gout_w   = (const float*)d_in[22];
    const float* gout_b   = (const float*)d_in[23];

    float* ws = (float*)d_ws;
    float* out = (float*)d_out;

    // ---- pack all recurrent weights (float4 [k/4][OUT] layout, K zero-padded) ----
    struct PW { const float* src; size_t off; int out, k, kpad; };
    const PW pws[15] = {
        {fwc_w,    W_FWC,     192, 328, 336}, {fwc_glu, W_FWCGLU, 192, 192, 192},
        {gout_w,   W_GOUT,      4, 192, 192}, {g1_ih,   W_G1IH,   480, 272, 272},
        {g1_hh,    W_G1HH,    480, 160, 160}, {glu1_w,  W_GLU1,   160, 160, 160},
        {g2_ih,    W_G2IH,    384, 240, 240}, {g2_hh,   W_G2HH,   384, 128, 128},
        {glu2_w,   W_GLU2,    128, 128, 128}, {g3_ih,   W_G3IH,   384, 208, 208},
        {g3_hh,    W_G3HH,    384, 128, 128}, {glu3_w,  W_GLU3,   128, 128, 128},
        {skip_w,   W_SKIP,    128, 688, 704}, {skip_glu,W_SKIPGLU,128, 128, 128},
        {sig_w,    W_SIG,      40, 128, 128},
    };
    for (int i = 0; i < 15; ++i) {
        int kp4 = pws[i].kpad / 4;
        int n = pws[i].out * kp4;
        k_pack<<<(n + 255) / 256, 256, 0, stream>>>(pws[i].src,
                                                    (float4*)(ws + OFF_W + pws[i].off),
                                                    pws[i].out, pws[i].k, kp4);
    }

    // ---- frontend ----
    {
        int n = 128 * 502 * 64;
        k_feat<<<(n + 255) / 256, 256, 0, stream>>>(features, period, pembed, fd1_w,
                                                    ws + OFF_X);
    }
    {
        int n = 128 * 500 * 128;
        k_conv<<<(n + 255) / 256, 256, 0, stream>>>(ws + OFF_X, fconv1_w, ws + OFF_Y);
    }
    k_cond<<<128 * 50, 320, 0, stream>>>(ws + OFF_Y, fd2_w, ws + OFF_COND);
    {
        int n = 128 * 2000;
        k_gain<<<(n + 255) / 256, 256, 0, stream>>>(ws + OFF_COND, cg_w, cg_b,
                                                    ws + OFF_GAIN);
    }

    // ---- recurrence ----
    fargan_main<<<128, 1024, 0, stream>>>(ws, period, gout_b, out);
}

// Round 3
// 47426.031 us; speedup vs baseline: 2.1023x; 1.3147x over previous
//
#include <hip/hip_runtime.h>
#include <hip/hip_fp16.h>
#include <math.h>

// ---------------------------------------------------------------------------
// FARGAN core. B=128, T=504, nb_frames=500, steps=2000, SUB=40.
// Round 3: fp16 weights (halves per-CU L2 traffic — the measured wall),
// fp32 activations + accumulation. uint4 loads carry 8 weights/lane.
// ---------------------------------------------------------------------------

#define DEV __device__ __forceinline__

DEV float sigm(float x) { return 1.0f / (1.0f + __expf(-x)); }
DEV float tanh_f(float x) { return 1.0f - 2.0f / (__expf(2.0f * x) + 1.0f); }

// ---- workspace layout (float offsets) ----
constexpr size_t STEPS = 2000;
constexpr size_t OFF_COND = 0;                                   // 128*500*320
constexpr size_t OFF_Y    = 20480000;                            // 128*500*128
constexpr size_t OFF_GAIN = OFF_Y + 8192000;                     // 128*2000
constexpr size_t OFF_W    = OFF_GAIN + 256000;                   // half-array base
constexpr size_t OFF_X    = OFF_COND;                            // aliases cond (dead)

// packed fp16 weights: OUT*KPAD halves, layout uint4[(k/8)*OUT + j]
constexpr size_t W_FWC     = 0;                       // 192 x 352
constexpr size_t W_FWCGLU  = W_FWC    + 192*352;      // 192 x 192
constexpr size_t W_GOUT    = W_FWCGLU + 192*192;      // 4   x 192
constexpr size_t W_G1IH    = W_GOUT   + 4*192;        // 480 x 272
constexpr size_t W_G1HH    = W_G1IH   + 480*272;      // 480 x 160
constexpr size_t W_GLU1    = W_G1HH   + 480*160;      // 160 x 160
constexpr size_t W_G2IH    = W_GLU1   + 160*160;      // 384 x 240
constexpr size_t W_G2HH    = W_G2IH   + 384*240;      // 384 x 128
constexpr size_t W_GLU2    = W_G2HH   + 384*128;      // 128 x 128
constexpr size_t W_G3IH    = W_GLU2   + 128*128;      // 384 x 208
constexpr size_t W_G3HH    = W_G3IH   + 384*208;      // 384 x 128
constexpr size_t W_GLU3    = W_G3HH   + 384*128;      // 128 x 128
constexpr size_t W_SKIP    = W_GLU3   + 128*128;      // 128 x 704
constexpr size_t W_SKIPGLU = W_SKIP   + 128*704;      // 128 x 128
constexpr size_t W_SIG     = W_SKIPGLU+ 128*128;      // 40  x 128

// ---------------------------------------------------------------------------
// pack fp32 -> fp16, layout uint4[(k/8)*OUT + j], zero pad past K
// ---------------------------------------------------------------------------
__global__ void k_pack_h(const float* __restrict__ src, __half* __restrict__ dst,
                         int OUT, int K, int KP8) {
    int t = blockIdx.x * 256 + threadIdx.x;
    if (t >= OUT * KP8) return;
    int j = t % OUT;
    int k8 = t / OUT;
    __half* d = dst + (size_t)t * 8;
#pragma unroll
    for (int i = 0; i < 8; ++i) {
        int k = k8 * 8 + i;
        d[i] = (k < K) ? __float2half(src[(size_t)j * K + k]) : __float2half(0.0f);
    }
}

// ---------------------------------------------------------------------------
// frontend (unchanged — verified correct)
// ---------------------------------------------------------------------------
__global__ void k_feat(const float* __restrict__ features, const int* __restrict__ period,
                       const float* __restrict__ pembed, const float* __restrict__ fd1,
                       float* __restrict__ xbuf) {
    int t = blockIdx.x * 256 + threadIdx.x;
    const int total = 128 * 502 * 64;
    if (t >= total) return;
    int o = t & 63;
    int r = t >> 6;
    int ft = r % 502;
    int b = r / 502;
    const float* f = features + ((size_t)b * 504 + ft + 2) * 20;
    int per = period[b * 504 + ft + 2];
    per = min(max(per, 32), 254);
    const float* pe = pembed + (per - 32) * 12;
    const float* w = fd1 + o * 32;
    float acc = 0.0f;
#pragma unroll
    for (int i = 0; i < 20; ++i) acc += f[i] * w[i];
#pragma unroll
    for (int i = 0; i < 12; ++i) acc += pe[i] * w[20 + i];
    xbuf[t] = tanh_f(acc);
}

__global__ void k_conv(const float* __restrict__ xbuf, const float* __restrict__ fconv1,
                       float* __restrict__ ybuf) {
    int t = blockIdx.x * 256 + threadIdx.x;
    const int total = 128 * 500 * 128;
    if (t >= total) return;
    int oc = t & 127;
    int r = t >> 7;
    int tt = r % 500;
    int b = r / 500;
    const float* xp = xbuf + ((size_t)b * 502 + tt) * 64;
    const float* w = fconv1 + oc * 192;
    float acc = 0.0f;
#pragma unroll 8
    for (int i = 0; i < 64; ++i) {
        acc += xp[i] * w[i * 3 + 0];
        acc += xp[64 + i] * w[i * 3 + 1];
        acc += xp[128 + i] * w[i * 3 + 2];
    }
    ybuf[t] = tanh_f(acc);
}

__global__ void k_cond(const float* __restrict__ ybuf, const float* __restrict__ fd2,
                       float* __restrict__ cond) {
    int b = blockIdx.x / 50;
    int t0 = (blockIdx.x % 50) * 10;
    int tid = threadIdx.x;
    __shared__ float yl[1280];
    for (int i = tid; i < 1280; i += 320)
        yl[i] = ybuf[((size_t)b * 500 + t0) * 128 + i];
    __syncthreads();
    const float* w = fd2 + tid * 128;
    float acc[10];
#pragma unroll
    for (int q = 0; q < 10; ++q) acc[q] = 0.0f;
#pragma unroll 4
    for (int k = 0; k < 128; ++k) {
        float wv = w[k];
#pragma unroll
        for (int q = 0; q < 10; ++q) acc[q] += wv * yl[q * 128 + k];
    }
#pragma unroll
    for (int q = 0; q < 10; ++q)
        cond[((size_t)b * 500 + t0 + q) * 320 + tid] = tanh_f(acc[q]);
}

__global__ void k_gain(const float* __restrict__ cond, const float* __restrict__ cgw,
                       const float* __restrict__ cgb, float* __restrict__ gains) {
    int t = blockIdx.x * 256 + threadIdx.x;
    const int total = 128 * 2000;
    if (t >= total) return;
    int s = t % 2000;
    int b = t / 2000;
    int frame = s >> 2, sub = s & 3;
    const float* c = cond + ((size_t)b * 500 + frame) * 320 + sub * 80;
    float acc = 0.0f;
#pragma unroll 8
    for (int i = 0; i < 80; ++i) acc += c[i] * cgw[i];
    float g = 0.2f + 0.8f * sigm(acc + cgb[0]);
    g = fminf(20.0f, fmaxf(0.001f, g));
    gains[t] = g;
}

// ---------------------------------------------------------------------------
// fp16 packed-matvec partial. WT layout: uint4[(k/8)*OUT + j] (8 halves each).
// x is fp32 in LDS, read as float4 pairs. No trailing barrier.
// ---------------------------------------------------------------------------
DEV float dot8(uint4 wv, float4 xa, float4 xb, float& a1) {
    float2 f0 = __half22float2(*(const __half2*)&wv.x);
    float2 f1 = __half22float2(*(const __half2*)&wv.y);
    float2 f2 = __half22float2(*(const __half2*)&wv.z);
    float2 f3 = __half22float2(*(const __half2*)&wv.w);
    float a0 = 0.0f;
    a0 += f0.x * xa.x; a1 += f0.y * xa.y;
    a0 += f1.x * xa.z; a1 += f1.y * xa.w;
    a0 += f2.x * xb.x; a1 += f2.y * xb.y;
    a0 += f3.x * xb.z; a1 += f3.y * xb.w;
    return a0;
}

template <int OUT, int KP8, int S>
DEV void mv_partial(const uint4* __restrict__ WT, const float* __restrict__ x,
                    float* __restrict__ part, int tid) {
    static_assert(KP8 % S == 0, "KP8 % S");
    static_assert(OUT * S <= 1024, "threads");
    constexpr int KS8 = KP8 / S;
    if (tid < OUT * S) {
        int j = tid % OUT;
        int sl = tid / OUT;
        const uint4* w = WT + (size_t)sl * KS8 * OUT + j;
        const float4* xx = (const float4*)x + (size_t)sl * KS8 * 2;
        float a0 = 0.0f, a1 = 0.0f;
#pragma unroll 4
        for (int k = 0; k < KS8; ++k) {
            uint4 wv = w[(size_t)k * OUT];
            a0 += dot8(wv, xx[2 * k], xx[2 * k + 1], a1);
        }
        part[tid] = a0 + a1;
    }
}

// GRU double partial (S=2): pa gets gi partials, pb gets gh partials
template <int OUT, int KP8A, int KP8B>
DEV void gru_partial(const uint4* __restrict__ wa, const float* __restrict__ xa,
                     const uint4* __restrict__ wb, const float* __restrict__ xb,
                     float* __restrict__ pa, float* __restrict__ pb, int tid) {
    static_assert((KP8A % 2 == 0) && (KP8B % 2 == 0), "even");
    constexpr int KA = KP8A / 2, KB = KP8B / 2;
    if (tid < OUT * 2) {
        int j = tid % OUT;
        int sl = tid / OUT;
        {
            const uint4* w = wa + (size_t)sl * KA * OUT + j;
            const float4* xx = (const float4*)xa + (size_t)sl * KA * 2;
            float a0 = 0.0f, a1 = 0.0f;
#pragma unroll 4
            for (int k = 0; k < KA; ++k) {
                uint4 wv = w[(size_t)k * OUT];
                a0 += dot8(wv, xx[2 * k], xx[2 * k + 1], a1);
            }
            pa[tid] = a0 + a1;
        }
        {
            const uint4* w = wb + (size_t)sl * KB * OUT + j;
            const float4* xx = (const float4*)xb + (size_t)sl * KB * 2;
            float b0 = 0.0f, b1 = 0.0f;
#pragma unroll 4
            for (int k = 0; k < KB; ++k) {
                uint4 wv = w[(size_t)k * OUT];
                b0 += dot8(wv, xx[2 * k], xx[2 * k + 1], b1);
            }
            pb[tid] = b0 + b1;
        }
    }
}

// GRU state update from partials (OUT = 3H, S = 2)
template <int H>
DEV void gru_update(const float* __restrict__ pa, const float* __restrict__ pb,
                    float* __restrict__ s, int tid) {
    constexpr int OUT = 3 * H;
    if (tid < H) {
        float gi_r = pa[tid] + pa[OUT + tid];
        float gh_r = pb[tid] + pb[OUT + tid];
        float gi_z = pa[H + tid] + pa[OUT + H + tid];
        float gh_z = pb[H + tid] + pb[OUT + H + tid];
        float gi_n = pa[2 * H + tid] + pa[OUT + 2 * H + tid];
        float gh_n = pb[2 * H + tid] + pb[OUT + 2 * H + tid];
        float r = sigm(gi_r + gh_r);
        float z = sigm(gi_z + gh_z);
        float n = tanh_f(gi_n + r * gh_n);
        s[tid] = (1.0f - z) * n + z * s[tid];
    }
}

// ---------------------------------------------------------------------------
// main recurrent kernel: 128 blocks x 1024 threads
// ---------------------------------------------------------------------------
__global__ __launch_bounds__(1024) void fargan_main(const float* __restrict__ ws,
                                                    const int* __restrict__ period,
                                                    const float* __restrict__ goutb,
                                                    float* __restrict__ out) {
    const int b = blockIdx.x;
    const int tid = threadIdx.x;

    const float* cond  = ws + OFF_COND;
    const float* gains = ws + OFF_GAIN;
    const __half* whb  = (const __half*)(ws + OFF_W);
    const uint4* wFWC     = (const uint4*)(whb + W_FWC);
    const uint4* wFWCGLU  = (const uint4*)(whb + W_FWCGLU);
    const uint4* wGOUT    = (const uint4*)(whb + W_GOUT);
    const uint4* wG1IH    = (const uint4*)(whb + W_G1IH);
    const uint4* wG1HH    = (const uint4*)(whb + W_G1HH);
    const uint4* wGLU1    = (const uint4*)(whb + W_GLU1);
    const uint4* wG2IH    = (const uint4*)(whb + W_G2IH);
    const uint4* wG2HH    = (const uint4*)(whb + W_G2HH);
    const uint4* wGLU2    = (const uint4*)(whb + W_GLU2);
    const uint4* wG3IH    = (const uint4*)(whb + W_G3IH);
    const uint4* wG3HH    = (const uint4*)(whb + W_G3HH);
    const uint4* wGLU3    = (const uint4*)(whb + W_GLU3);
    const uint4* wSKIP    = (const uint4*)(whb + W_SKIP);
    const uint4* wSKIPGLU = (const uint4*)(whb + W_SKIPGLU);
    const uint4* wSIG     = (const uint4*)(whb + W_SIG);

    // xcat: [fwc_state 0..163 | cond80 164..243 | pred 244..287 | prev 288..327 | pad..351]
    __shared__ __align__(16) float xcat[352];
    __shared__ __align__(16) float exc[256];
    __shared__ __align__(16) float s1[160], s2[128], s3[128];
    __shared__ __align__(16) float partA[1024], partB[1024];
    __shared__ __align__(16) float fwcpre[192], fwcout[192];
    __shared__ __align__(16) float pg[4];
    __shared__ __align__(16) float inb[272];
    __shared__ __align__(16) float g1[160], g2[128], g3[128];
    __shared__ __align__(16) float skipin[704], skippre[128], skipout[128];
    __shared__ __align__(16) float sigraw[40];

    // zero-init
    for (int i = tid; i < 256; i += 1024) exc[i] = 0.0f;
    if (tid < 160) s1[tid] = 0.0f;
    if (tid < 128) { s2[tid] = 0.0f; s3[tid] = 0.0f; }
    if (tid < 164) xcat[tid] = 0.0f;
    if (tid >= 328 && tid < 352) xcat[tid] = 0.0f;          // fwc K-pad
    if (tid >= 688 && tid < 704) skipin[tid] = 0.0f;        // skip K-pad
    __syncthreads();

    for (int s = 0; s < (int)STEPS; ++s) {
        const int frame = s >> 2;
        const float gain = gains[(size_t)b * 2000 + s];
        const float ig = 1.0f / (1e-5f + gain);
        int per = period[b * 504 + 3 + frame];
        per = min(max(per, 32), 254);

        // Phase A: gather cond80, pred, prev into xcat
        if (tid < 80) {
            xcat[164 + tid] = cond[((size_t)b * 500 + frame) * 320 + (s & 3) * 80 + tid];
        } else if (tid >= 128 && tid < 172) {
            int j = tid - 128;
            int idx = 254 - per + j;
            if (idx >= 256) idx -= per;
            idx = min(255, max(0, idx));
            xcat[244 + j] = exc[idx] * ig;
        } else if (tid >= 192 && tid < 232) {
            xcat[288 + tid - 192] = exc[216 + tid - 192] * ig;
        }
        __syncthreads();

        // Phase B: fwc partial (OUT=192, KPAD=352 -> KP8=44, S=4, 768 thr)
        mv_partial<192, 44, 4>(wFWC, xcat, partA, tid);
        __syncthreads();
        // Phase C: reduce -> fwcpre = tanh
        if (tid < 192) {
            float a = partA[tid] + partA[192 + tid] + partA[384 + tid] + partA[576 + tid];
            fwcpre[tid] = tanh_f(a);
        }
        __syncthreads();

        // Phase D: fwcglu partial (768 thr) || gout partial (32 thr) || xcat shift
        mv_partial<192, 24, 4>(wFWCGLU, fwcpre, partA, tid);
        if (tid >= 768 && tid < 800) {
            int t2 = tid - 768;
            int j = t2 & 3, sl = t2 >> 2;           // OUT=4, KP8=24, 8 slices of 3
            const uint4* w = wGOUT + (sl * 3) * 4 + j;
            const float4* xx = (const float4*)fwcpre + sl * 6;
            float a0 = 0.0f, a1 = 0.0f;
#pragma unroll
            for (int k = 0; k < 3; ++k) {
                uint4 wv = w[k * 4];
                a0 += dot8(wv, xx[2 * k], xx[2 * k + 1], a1);
            }
            partB[t2] = a0 + a1;
        } else if (tid >= 832 && tid < 996) {
            xcat[tid - 832] = xcat[tid - 832 + 164];   // fwc_state' shift
        }
        __syncthreads();

        // Phase E: fwcout + pg + inb(gru1) build
        if (tid < 192) {
            float a = partA[tid] + partA[192 + tid] + partA[384 + tid] + partA[576 + tid];
            float v = fwcpre[tid] * sigm(a);
            fwcout[tid] = v;
            inb[tid] = v;
        } else if (tid < 232) {
            // redundant pg0 recompute breaks cross-thread dependency in-phase
            float a = goutb[0];
#pragma unroll
            for (int sl = 0; sl < 8; ++sl) a += partB[sl * 4];
            inb[tid] = sigm(a) * xcat[246 + tid - 192];
        } else if (tid < 272) {
            inb[tid] = xcat[288 + tid - 232];
        } else if (tid >= 960 && tid < 964) {
            int j = tid - 960;
            float a = goutb[j];
#pragma unroll
            for (int sl = 0; sl < 8; ++sl) a += partB[sl * 4 + j];
            pg[j] = sigm(a);
        }
        __syncthreads();

        // Phase F/G: GRU1 (H=160, OUT=480; K 272/160 -> KP8 34/20)
        gru_partial<480, 34, 20>(wG1IH, inb, wG1HH, s1, partA, partB, tid);
        __syncthreads();
        gru_update<160>(partA, partB, s1, tid);
        __syncthreads();

        // Phase H/I: GLU1 (160x160, KP8=20, S=4) + inb(gru2) build
        mv_partial<160, 20, 4>(wGLU1, s1, partA, tid);
        __syncthreads();
        if (tid < 160) {
            float a = partA[tid] + partA[160 + tid] + partA[320 + tid] + partA[480 + tid];
            float v = s1[tid] * sigm(a);
            g1[tid] = v;
            inb[tid] = v;
        } else if (tid < 200) {
            inb[tid] = pg[1] * xcat[246 + tid - 160];
        } else if (tid < 240) {
            inb[tid] = xcat[288 + tid - 200];
        }
        __syncthreads();

        // Phase J/K: GRU2 (H=128, OUT=384; K 240/128 -> KP8 30/16)
        gru_partial<384, 30, 16>(wG2IH, inb, wG2HH, s2, partA, partB, tid);
        __syncthreads();
        gru_update<128>(partA, partB, s2, tid);
        __syncthreads();

        // Phase L/M: GLU2 (128x128, KP8=16, S=8) + inb(gru3) build
        mv_partial<128, 16, 8>(wGLU2, s2, partA, tid);
        __syncthreads();
        if (tid < 128) {
            float a = 0.0f;
#pragma unroll
            for (int sl = 0; sl < 8; ++sl) a += partA[sl * 128 + tid];
            float v = s2[tid] * sigm(a);
            g2[tid] = v;
            inb[tid] = v;
        } else if (tid < 168) {
            inb[tid] = pg[2] * xcat[246 + tid - 128];
        } else if (tid < 208) {
            inb[tid] = xcat[288 + tid - 168];
        }
        __syncthreads();

        // Phase N/O: GRU3 (H=128, OUT=384; K 208/128 -> KP8 26/16)
        gru_partial<384, 26, 16>(wG3IH, inb, wG3HH, s3, partA, partB, tid);
        __syncthreads();
        gru_update<128>(partA, partB, s3, tid);
        __syncthreads();

        // Phase P/Q: GLU3 + skipin build
        mv_partial<128, 16, 8>(wGLU3, s3, partA, tid);
        __syncthreads();
        // skipin: [g1 0..159 | g2 160..287 | g3 288..415 | fwcout 416..607 | pitch 608..647 | prev 648..687]
        if (tid < 128) {
            float a = 0.0f;
#pragma unroll
            for (int sl = 0; sl < 8; ++sl) a += partA[sl * 128 + tid];
            float v = s3[tid] * sigm(a);
            g3[tid] = v;
            skipin[288 + tid] = v;
        } else if (tid < 288) {
            skipin[tid - 128] = g1[tid - 128];
        } else if (tid < 416) {
            skipin[160 + tid - 288] = g2[tid - 288];
        } else if (tid < 608) {
            skipin[416 + tid - 416] = fwcout[tid - 416];
        } else if (tid < 648) {
            skipin[tid] = pg[3] * xcat[246 + tid - 608];
        } else if (tid < 688) {
            skipin[tid] = xcat[288 + tid - 648];
        }
        __syncthreads();

        // Phase R/S: skip (128x688, KPAD=704 -> KP8=88, S=8)
        mv_partial<128, 88, 8>(wSKIP, skipin, partA, tid);
        __syncthreads();
        if (tid < 128) {
            float a = 0.0f;
#pragma unroll
            for (int sl = 0; sl < 8; ++sl) a += partA[sl * 128 + tid];
            skippre[tid] = tanh_f(a);
        }
        __syncthreads();

        // Phase T/U: skipglu (128x128)
        mv_partial<128, 16, 8>(wSKIPGLU, skippre, partA, tid);
        __syncthreads();
        if (tid < 128) {
            float a = 0.0f;
#pragma unroll
            for (int sl = 0; sl < 8; ++sl) a += partA[sl * 128 + tid];
            skipout[tid] = skippre[tid] * sigm(a);
        }
        __syncthreads();

        // Phase V: sig partial (40x128, KP8=16, S=8, 320 thr)
        mv_partial<40, 16, 8>(wSIG, skipout, partA, tid);
        __syncthreads();
        // Phase W: sig reduce + read old exc
        float keep = (tid < 216) ? exc[tid + 40] : 0.0f;
        if (tid < 40) {
            float a = 0.0f;
#pragma unroll
            for (int sl = 0; sl < 8; ++sl) a += partA[sl * 40 + tid];
            sigraw[tid] = tanh_f(a) * gain;
        }
        __syncthreads();
        // Phase X: exc shift + output
        if (tid < 216) {
            exc[tid] = keep;
        } else if (tid < 256) {
            float sv = sigraw[tid - 216];
            exc[tid] = sv;
            out[(size_t)b * 80000 + (size_t)s * 40 + (tid - 216)] = sv;
        }
        __syncthreads();
    }
}

// ---------------------------------------------------------------------------
extern "C" void kernel_launch(void* const* d_in, const int* in_sizes, int n_in,
                              void* d_out, int out_size, void* d_ws, size_t ws_size,
                              hipStream_t stream) {
    const float* features = (const float*)d_in[0];
    const int*   period   = (const int*)d_in[1];
    const float* pembed   = (const float*)d_in[2];
    const float* fd1_w    = (const float*)d_in[3];
    const float* fconv1_w = (const float*)d_in[4];
    const float* fd2_w    = (const float*)d_in[5];
    const float* cg_w     = (const float*)d_in[6];
    const float* cg_b     = (const float*)d_in[7];
    const float* fwc_w    = (const float*)d_in[8];
    const float* fwc_glu  = (const float*)d_in[9];
    const float* g1_ih    = (const float*)d_in[10];
    const float* g1_hh    = (const float*)d_in[11];
    const float* glu1_w   = (const float*)d_in[12];
    const float* g2_ih    = (const float*)d_in[13];
    const float* g2_hh    = (const float*)d_in[14];
    const float* glu2_w   = (const float*)d_in[15];
    const float* g3_ih    = (const float*)d_in[16];
    const float* g3_hh    = (const float*)d_in[17];
    const float* glu3_w   = (const float*)d_in[18];
    const float* skip_w   = (const float*)d_in[19];
    const float* skip_glu = (const float*)d_in[20];
    const float* sig_w    = (const float*)d_in[21];
    const float* gout_w   = (const float*)d_in[22];
    const float* gout_b   = (const float*)d_in[23];

    float* ws = (float*)d_ws;
    float* out = (float*)d_out;
    __half* wh = (__half*)(ws + OFF_W);

    // ---- pack all recurrent weights to fp16 ([k/8][OUT] uint4 layout) ----
    struct PW { const float* src; size_t off; int out, k, kpad; };
    const PW pws[15] = {
        {fwc_w,    W_FWC,     192, 328, 352}, {fwc_glu, W_FWCGLU, 192, 192, 192},
        {gout_w,   W_GOUT,      4, 192, 192}, {g1_ih,   W_G1IH,   480, 272, 272},
        {g1_hh,    W_G1HH,    480, 160, 160}, {glu1_w,  W_GLU1,   160, 160, 160},
        {g2_ih,    W_G2IH,    384, 240, 240}, {g2_hh,   W_G2HH,   384, 128, 128},
        {glu2_w,   W_GLU2,    128, 128, 128}, {g3_ih,   W_G3IH,   384, 208, 208},
        {g3_hh,    W_G3HH,    384, 128, 128}, {glu3_w,  W_GLU3,   128, 128, 128},
        {skip_w,   W_SKIP,    128, 688, 704}, {skip_glu,W_SKIPGLU,128, 128, 128},
        {sig_w,    W_SIG,      40, 128, 128},
    };
    for (int i = 0; i < 15; ++i) {
        int kp8 = pws[i].kpad / 8;
        int n = pws[i].out * kp8;
        k_pack_h<<<(n + 255) / 256, 256, 0, stream>>>(pws[i].src, wh + pws[i].off,
                                                      pws[i].out, pws[i].k, kp8);
    }

    // ---- frontend ----
    {
        int n = 128 * 502 * 64;
        k_feat<<<(n + 255) / 256, 256, 0, stream>>>(features, period, pembed, fd1_w,
                                                    ws + OFF_X);
    }
    {
        int n = 128 * 500 * 128;
        k_conv<<<(n + 255) / 256, 256, 0, stream>>>(ws + OFF_X, fconv1_w, ws + OFF_Y);
    }
    k_cond<<<128 * 50, 320, 0, stream>>>(ws + OFF_Y, fd2_w, ws + OFF_COND);
    {
        int n = 128 * 2000;
        k_gain<<<(n + 255) / 256, 256, 0, stream>>>(ws + OFF_COND, cg_w, cg_b,
                                                    ws + OFF_GAIN);
    }

    // ---- recurrence ----
    fargan_main<<<128, 1024, 0, stream>>>(ws, period, gout_b, out);
}

// Round 4
// 36204.199 us; speedup vs baseline: 2.7540x; 1.3100x over previous
//
#include <hip/hip_runtime.h>
#include <hip/hip_fp16.h>
#include <math.h>

// ---------------------------------------------------------------------------
// FARGAN core. B=128, T=504, nb_frames=500, steps=2000, SUB=40.
// Round 4: fp16 weights AND fp16 matvec activations with v_dot2_f32_f16
// (fp32 accumulate). State masters (exc, s1-3, partials, output) stay fp32.
// Per weight-uint4: 1 global uint4 + 1 ds_read_b128 + 4 fdot2. No cvt.
// ---------------------------------------------------------------------------

#define DEV __device__ __forceinline__

DEV float sigm(float x) { return 1.0f / (1.0f + __expf(-x)); }
DEV float tanh_f(float x) { return 1.0f - 2.0f / (__expf(2.0f * x) + 1.0f); }

typedef _Float16 h2v __attribute__((ext_vector_type(2)));

#if defined(__has_builtin)
#if __has_builtin(__builtin_amdgcn_fdot2)
#define HAVE_FDOT2 1
#endif
#endif

DEV float fdot2(h2v a, h2v b, float c) {
#ifdef HAVE_FDOT2
    return __builtin_amdgcn_fdot2(a, b, c, false);
#else
    return c + (float)a[0] * (float)b[0] + (float)a[1] * (float)b[1];
#endif
}

// ---- workspace layout (float offsets) ----
constexpr size_t STEPS = 2000;
constexpr size_t OFF_X     = 0;          // 128*502*64 f32 = 4,112,384
constexpr size_t OFF_Y     = 4200000;    // 128*500*128 f32 = 8,192,000
constexpr size_t OFF_GAIN  = 12392000;   // 128*2000 f32
constexpr size_t OFF_CONDH = 12648000;   // 128*500*320 halves = 10,240,000 f32-units
constexpr size_t OFF_W     = 22888000;   // fp16 weights, 752,896 halves

// packed fp16 weights: OUT*KPAD halves, layout uint4[(k/8)*OUT + j]
constexpr size_t W_FWC     = 0;                       // 192 x 352
constexpr size_t W_FWCGLU  = W_FWC    + 192*352;      // 192 x 192
constexpr size_t W_GOUT    = W_FWCGLU + 192*192;      // 4   x 192
constexpr size_t W_G1IH    = W_GOUT   + 4*192;        // 480 x 272
constexpr size_t W_G1HH    = W_G1IH   + 480*272;      // 480 x 160
constexpr size_t W_GLU1    = W_G1HH   + 480*160;      // 160 x 160
constexpr size_t W_G2IH    = W_GLU1   + 160*160;      // 384 x 240
constexpr size_t W_G2HH    = W_G2IH   + 384*240;      // 384 x 128
constexpr size_t W_GLU2    = W_G2HH   + 384*128;      // 128 x 128
constexpr size_t W_G3IH    = W_GLU2   + 128*128;      // 384 x 208
constexpr size_t W_G3HH    = W_G3IH   + 384*208;      // 384 x 128
constexpr size_t W_GLU3    = W_G3HH   + 384*128;      // 128 x 128
constexpr size_t W_SKIP    = W_GLU3   + 128*128;      // 128 x 704
constexpr size_t W_SKIPGLU = W_SKIP   + 128*704;      // 128 x 128
constexpr size_t W_SIG     = W_SKIPGLU+ 128*128;      // 40  x 128

// ---------------------------------------------------------------------------
// pack fp32 -> fp16, layout uint4[(k/8)*OUT + j], zero pad past K
// ---------------------------------------------------------------------------
__global__ void k_pack_h(const float* __restrict__ src, __half* __restrict__ dst,
                         int OUT, int K, int KP8) {
    int t = blockIdx.x * 256 + threadIdx.x;
    if (t >= OUT * KP8) return;
    int j = t % OUT;
    int k8 = t / OUT;
    __half* d = dst + (size_t)t * 8;
#pragma unroll
    for (int i = 0; i < 8; ++i) {
        int k = k8 * 8 + i;
        d[i] = (k < K) ? __float2half(src[(size_t)j * K + k]) : __float2half(0.0f);
    }
}

// ---------------------------------------------------------------------------
// frontend
// ---------------------------------------------------------------------------
__global__ void k_feat(const float* __restrict__ features, const int* __restrict__ period,
                       const float* __restrict__ pembed, const float* __restrict__ fd1,
                       float* __restrict__ xbuf) {
    int t = blockIdx.x * 256 + threadIdx.x;
    const int total = 128 * 502 * 64;
    if (t >= total) return;
    int o = t & 63;
    int r = t >> 6;
    int ft = r % 502;
    int b = r / 502;
    const float* f = features + ((size_t)b * 504 + ft + 2) * 20;
    int per = period[b * 504 + ft + 2];
    per = min(max(per, 32), 254);
    const float* pe = pembed + (per - 32) * 12;
    const float* w = fd1 + o * 32;
    float acc = 0.0f;
#pragma unroll
    for (int i = 0; i < 20; ++i) acc += f[i] * w[i];
#pragma unroll
    for (int i = 0; i < 12; ++i) acc += pe[i] * w[20 + i];
    xbuf[t] = tanh_f(acc);
}

__global__ void k_conv(const float* __restrict__ xbuf, const float* __restrict__ fconv1,
                       float* __restrict__ ybuf) {
    int t = blockIdx.x * 256 + threadIdx.x;
    const int total = 128 * 500 * 128;
    if (t >= total) return;
    int oc = t & 127;
    int r = t >> 7;
    int tt = r % 500;
    int b = r / 500;
    const float* xp = xbuf + ((size_t)b * 502 + tt) * 64;
    const float* w = fconv1 + oc * 192;
    float acc = 0.0f;
#pragma unroll 8
    for (int i = 0; i < 64; ++i) {
        acc += xp[i] * w[i * 3 + 0];
        acc += xp[64 + i] * w[i * 3 + 1];
        acc += xp[128 + i] * w[i * 3 + 2];
    }
    ybuf[t] = tanh_f(acc);
}

// cond written as fp16
__global__ void k_cond(const float* __restrict__ ybuf, const float* __restrict__ fd2,
                       __half* __restrict__ cond) {
    int b = blockIdx.x / 50;
    int t0 = (blockIdx.x % 50) * 10;
    int tid = threadIdx.x;
    __shared__ float yl[1280];
    for (int i = tid; i < 1280; i += 320)
        yl[i] = ybuf[((size_t)b * 500 + t0) * 128 + i];
    __syncthreads();
    const float* w = fd2 + tid * 128;
    float acc[10];
#pragma unroll
    for (int q = 0; q < 10; ++q) acc[q] = 0.0f;
#pragma unroll 4
    for (int k = 0; k < 128; ++k) {
        float wv = w[k];
#pragma unroll
        for (int q = 0; q < 10; ++q) acc[q] += wv * yl[q * 128 + k];
    }
#pragma unroll
    for (int q = 0; q < 10; ++q)
        cond[((size_t)b * 500 + t0 + q) * 320 + tid] = __float2half(tanh_f(acc[q]));
}

__global__ void k_gain(const __half* __restrict__ cond, const float* __restrict__ cgw,
                       const float* __restrict__ cgb, float* __restrict__ gains) {
    int t = blockIdx.x * 256 + threadIdx.x;
    const int total = 128 * 2000;
    if (t >= total) return;
    int s = t % 2000;
    int b = t / 2000;
    int frame = s >> 2, sub = s & 3;
    const __half* c = cond + ((size_t)b * 500 + frame) * 320 + sub * 80;
    float acc = 0.0f;
#pragma unroll 8
    for (int i = 0; i < 80; ++i) acc += __half2float(c[i]) * cgw[i];
    float g = 0.2f + 0.8f * sigm(acc + cgb[0]);
    g = fminf(20.0f, fmaxf(0.001f, g));
    gains[t] = g;
}

// ---------------------------------------------------------------------------
// 8-wide fp16 dot: w-uint4 (8 halves) x x-uint4 (8 halves), 2 f32 accs
// ---------------------------------------------------------------------------
DEV void dot8h(uint4 w, uint4 x, float& a0, float& a1) {
    const h2v* wv = (const h2v*)&w;
    const h2v* xv = (const h2v*)&x;
    a0 = fdot2(wv[0], xv[0], a0);
    a1 = fdot2(wv[1], xv[1], a1);
    a0 = fdot2(wv[2], xv[2], a0);
    a1 = fdot2(wv[3], xv[3], a1);
}

// fp16 packed-matvec partial. WT: uint4[(k/8)*OUT + j]. x: __half LDS, 16B-aligned.
template <int OUT, int KP8, int S>
DEV void mv_partial(const uint4* __restrict__ WT, const __half* __restrict__ x,
                    float* __restrict__ part, int tid) {
    static_assert(KP8 % S == 0, "KP8 % S");
    static_assert(OUT * S <= 1024, "threads");
    constexpr int KS8 = KP8 / S;
    if (tid < OUT * S) {
        int j = tid % OUT;
        int sl = tid / OUT;
        const uint4* w = WT + (size_t)sl * KS8 * OUT + j;
        const uint4* xx = (const uint4*)x + (size_t)sl * KS8;
        float a0 = 0.0f, a1 = 0.0f;
#pragma unroll 4
        for (int k = 0; k < KS8; ++k) {
            dot8h(w[(size_t)k * OUT], xx[k], a0, a1);
        }
        part[tid] = a0 + a1;
    }
}

// GRU double partial (S=2)
template <int OUT, int KP8A, int KP8B>
DEV void gru_partial(const uint4* __restrict__ wa, const __half* __restrict__ xa,
                     const uint4* __restrict__ wb, const __half* __restrict__ xb,
                     float* __restrict__ pa, float* __restrict__ pb, int tid) {
    static_assert((KP8A % 2 == 0) && (KP8B % 2 == 0), "even");
    constexpr int KA = KP8A / 2, KB = KP8B / 2;
    if (tid < OUT * 2) {
        int j = tid % OUT;
        int sl = tid / OUT;
        {
            const uint4* w = wa + (size_t)sl * KA * OUT + j;
            const uint4* xx = (const uint4*)xa + (size_t)sl * KA;
            float a0 = 0.0f, a1 = 0.0f;
#pragma unroll 4
            for (int k = 0; k < KA; ++k) dot8h(w[(size_t)k * OUT], xx[k], a0, a1);
            pa[tid] = a0 + a1;
        }
        {
            const uint4* w = wb + (size_t)sl * KB * OUT + j;
            const uint4* xx = (const uint4*)xb + (size_t)sl * KB;
            float b0 = 0.0f, b1 = 0.0f;
#pragma unroll 4
            for (int k = 0; k < KB; ++k) dot8h(w[(size_t)k * OUT], xx[k], b0, b1);
            pb[tid] = b0 + b1;
        }
    }
}

// GRU state update from partials; fp32 master + fp16 mirror
template <int H>
DEV void gru_update(const float* __restrict__ pa, const float* __restrict__ pb,
                    float* __restrict__ s, __half* __restrict__ sh, int tid) {
    constexpr int OUT = 3 * H;
    if (tid < H) {
        float gi_r = pa[tid] + pa[OUT + tid];
        float gh_r = pb[tid] + pb[OUT + tid];
        float gi_z = pa[H + tid] + pa[OUT + H + tid];
        float gh_z = pb[H + tid] + pb[OUT + H + tid];
        float gi_n = pa[2 * H + tid] + pa[OUT + 2 * H + tid];
        float gh_n = pb[2 * H + tid] + pb[OUT + 2 * H + tid];
        float r = sigm(gi_r + gh_r);
        float z = sigm(gi_z + gh_z);
        float n = tanh_f(gi_n + r * gh_n);
        float v = (1.0f - z) * n + z * s[tid];
        s[tid] = v;
        sh[tid] = __float2half(v);
    }
}

// ---------------------------------------------------------------------------
// main recurrent kernel: 128 blocks x 1024 threads
// ---------------------------------------------------------------------------
__global__ __launch_bounds__(1024) void fargan_main(const float* __restrict__ ws,
                                                    const int* __restrict__ period,
                                                    const float* __restrict__ goutb,
                                                    float* __restrict__ out) {
    const int b = blockIdx.x;
    const int tid = threadIdx.x;

    const __half* cond = (const __half*)(ws + OFF_CONDH);
    const float* gains = ws + OFF_GAIN;
    const __half* whb  = (const __half*)(ws + OFF_W);
    const uint4* wFWC     = (const uint4*)(whb + W_FWC);
    const uint4* wFWCGLU  = (const uint4*)(whb + W_FWCGLU);
    const uint4* wGOUT    = (const uint4*)(whb + W_GOUT);
    const uint4* wG1IH    = (const uint4*)(whb + W_G1IH);
    const uint4* wG1HH    = (const uint4*)(whb + W_G1HH);
    const uint4* wGLU1    = (const uint4*)(whb + W_GLU1);
    const uint4* wG2IH    = (const uint4*)(whb + W_G2IH);
    const uint4* wG2HH    = (const uint4*)(whb + W_G2HH);
    const uint4* wGLU2    = (const uint4*)(whb + W_GLU2);
    const uint4* wG3IH    = (const uint4*)(whb + W_G3IH);
    const uint4* wG3HH    = (const uint4*)(whb + W_G3HH);
    const uint4* wGLU3    = (const uint4*)(whb + W_GLU3);
    const uint4* wSKIP    = (const uint4*)(whb + W_SKIP);
    const uint4* wSKIPGLU = (const uint4*)(whb + W_SKIPGLU);
    const uint4* wSIG     = (const uint4*)(whb + W_SIG);

    // fp16 matvec inputs
    __shared__ __align__(16) __half xcat_h[352];   // [state 0..163|cond 164..243|pred 244..287|prev 288..327|pad]
    __shared__ __align__(16) __half inb_h[272];
    __shared__ __align__(16) __half fwcpre_h[192], fwcout_h[192];
    __shared__ __align__(16) __half s1_h[160], s2_h[128], s3_h[128];
    __shared__ __align__(16) __half g1_h[160], g2_h[128], g3_h[128];
    __shared__ __align__(16) __half skipin_h[704], skippre_h[128], skipout_h[128];
    // fp32 masters
    __shared__ __align__(16) float exc[256];
    __shared__ __align__(16) float s1[160], s2[128], s3[128];
    __shared__ __align__(16) float partA[1024], partB[1024];
    __shared__ __align__(16) float fwcpre[192];
    __shared__ __align__(16) float pg[4];
    __shared__ __align__(16) float skippre[128];
    __shared__ __align__(16) float sigraw[40];

    // zero-init
    for (int i = tid; i < 256; i += 1024) exc[i] = 0.0f;
    if (tid < 160) { s1[tid] = 0.0f; s1_h[tid] = __float2half(0.0f); }
    if (tid < 128) { s2[tid] = 0.0f; s3[tid] = 0.0f;
                     s2_h[tid] = __float2half(0.0f); s3_h[tid] = __float2half(0.0f); }
    if (tid < 164) xcat_h[tid] = __float2half(0.0f);
    if (tid >= 328 && tid < 352) xcat_h[tid] = __float2half(0.0f);   // fwc K-pad
    if (tid >= 688 && tid < 704) skipin_h[tid] = __float2half(0.0f); // skip K-pad
    __syncthreads();

    for (int s = 0; s < (int)STEPS; ++s) {
        const int frame = s >> 2;
        const float gain = gains[(size_t)b * 2000 + s];
        const float ig = 1.0f / (1e-5f + gain);
        int per = period[b * 504 + 3 + frame];
        per = min(max(per, 32), 254);

        // Phase A: gather cond80, pred, prev into xcat_h
        if (tid < 80) {
            xcat_h[164 + tid] = cond[((size_t)b * 500 + frame) * 320 + (s & 3) * 80 + tid];
        } else if (tid >= 128 && tid < 172) {
            int j = tid - 128;
            int idx = 254 - per + j;
            if (idx >= 256) idx -= per;
            idx = min(255, max(0, idx));
            xcat_h[244 + j] = __float2half(exc[idx] * ig);
        } else if (tid >= 192 && tid < 232) {
            xcat_h[288 + tid - 192] = __float2half(exc[216 + tid - 192] * ig);
        }
        __syncthreads();

        // Phase B: fwc partial (OUT=192, KPAD=352 -> KP8=44, S=4, 768 thr)
        mv_partial<192, 44, 4>(wFWC, xcat_h, partA, tid);
        __syncthreads();
        // Phase C: reduce -> fwcpre = tanh (f32 + h mirror)
        if (tid < 192) {
            float a = partA[tid] + partA[192 + tid] + partA[384 + tid] + partA[576 + tid];
            float t = tanh_f(a);
            fwcpre[tid] = t;
            fwcpre_h[tid] = __float2half(t);
        }
        __syncthreads();

        // Phase D: fwcglu partial (768 thr) || gout partial (32 thr) || xcat shift
        mv_partial<192, 24, 4>(wFWCGLU, fwcpre_h, partA, tid);
        if (tid >= 768 && tid < 800) {
            int t2 = tid - 768;
            int j = t2 & 3, sl = t2 >> 2;           // OUT=4, KP8=24, 8 slices of 3
            const uint4* w = wGOUT + (sl * 3) * 4 + j;
            const uint4* xx = (const uint4*)fwcpre_h + sl * 3;
            float a0 = 0.0f, a1 = 0.0f;
#pragma unroll
            for (int k = 0; k < 3; ++k) dot8h(w[k * 4], xx[k], a0, a1);
            partB[t2] = a0 + a1;
        } else if (tid >= 832 && tid < 996) {
            xcat_h[tid - 832] = xcat_h[tid - 832 + 164];   // fwc_state' shift
        }
        __syncthreads();

        // Phase E: fwcout + pg + inb(gru1) build
        if (tid < 192) {
            float a = partA[tid] + partA[192 + tid] + partA[384 + tid] + partA[576 + tid];
            float v = fwcpre[tid] * sigm(a);
            __half vh = __float2half(v);
            fwcout_h[tid] = vh;
            inb_h[tid] = vh;
        } else if (tid < 232) {
            // redundant pg0 recompute breaks cross-thread dependency in-phase
            float a = goutb[0];
#pragma unroll
            for (int sl = 0; sl < 8; ++sl) a += partB[sl * 4];
            inb_h[tid] = __float2half(sigm(a) * __half2float(xcat_h[246 + tid - 192]));
        } else if (tid < 272) {
            inb_h[tid] = xcat_h[288 + tid - 232];
        } else if (tid >= 960 && tid < 964) {
            int j = tid - 960;
            float a = goutb[j];
#pragma unroll
            for (int sl = 0; sl < 8; ++sl) a += partB[sl * 4 + j];
            pg[j] = sigm(a);
        }
        __syncthreads();

        // Phase F/G: GRU1 (H=160, OUT=480; KP8 34/20)
        gru_partial<480, 34, 20>(wG1IH, inb_h, wG1HH, s1_h, partA, partB, tid);
        __syncthreads();
        gru_update<160>(partA, partB, s1, s1_h, tid);
        __syncthreads();

        // Phase H/I: GLU1 (160x160, KP8=20, S=4) + inb(gru2) build
        mv_partial<160, 20, 4>(wGLU1, s1_h, partA, tid);
        __syncthreads();
        if (tid < 160) {
            float a = partA[tid] + partA[160 + tid] + partA[320 + tid] + partA[480 + tid];
            float v = s1[tid] * sigm(a);
            __half vh = __float2half(v);
            g1_h[tid] = vh;
            inb_h[tid] = vh;
        } else if (tid < 200) {
            inb_h[tid] = __float2half(pg[1] * __half2float(xcat_h[246 + tid - 160]));
        } else if (tid < 240) {
            inb_h[tid] = xcat_h[288 + tid - 200];
        }
        __syncthreads();

        // Phase J/K: GRU2 (H=128, OUT=384; KP8 30/16)
        gru_partial<384, 30, 16>(wG2IH, inb_h, wG2HH, s2_h, partA, partB, tid);
        __syncthreads();
        gru_update<128>(partA, partB, s2, s2_h, tid);
        __syncthreads();

        // Phase L/M: GLU2 (128x128, KP8=16, S=8) + inb(gru3) build
        mv_partial<128, 16, 8>(wGLU2, s2_h, partA, tid);
        __syncthreads();
        if (tid < 128) {
            float a = 0.0f;
#pragma unroll
            for (int sl = 0; sl < 8; ++sl) a += partA[sl * 128 + tid];
            float v = s2[tid] * sigm(a);
            __half vh = __float2half(v);
            g2_h[tid] = vh;
            inb_h[tid] = vh;
        } else if (tid < 168) {
            inb_h[tid] = __float2half(pg[2] * __half2float(xcat_h[246 + tid - 128]));
        } else if (tid < 208) {
            inb_h[tid] = xcat_h[288 + tid - 168];
        }
        __syncthreads();

        // Phase N/O: GRU3 (H=128, OUT=384; KP8 26/16)
        gru_partial<384, 26, 16>(wG3IH, inb_h, wG3HH, s3_h, partA, partB, tid);
        __syncthreads();
        gru_update<128>(partA, partB, s3, s3_h, tid);
        __syncthreads();

        // Phase P/Q: GLU3 + skipin build
        mv_partial<128, 16, 8>(wGLU3, s3_h, partA, tid);
        __syncthreads();
        // skipin: [g1 0..159 | g2 160..287 | g3 288..415 | fwcout 416..607 | pitch 608..647 | prev 648..687]
        if (tid < 128) {
            float a = 0.0f;
#pragma unroll
            for (int sl = 0; sl < 8; ++sl) a += partA[sl * 128 + tid];
            float v = s3[tid] * sigm(a);
            __half vh = __float2half(v);
            g3_h[tid] = vh;
            skipin_h[288 + tid] = vh;
        } else if (tid < 288) {
            skipin_h[tid - 128] = g1_h[tid - 128];
        } else if (tid < 416) {
            skipin_h[160 + tid - 288] = g2_h[tid - 288];
        } else if (tid < 608) {
            skipin_h[tid] = fwcout_h[tid - 416];
        } else if (tid < 648) {
            skipin_h[tid] = __float2half(pg[3] * __half2float(xcat_h[246 + tid - 608]));
        } else if (tid < 688) {
            skipin_h[tid] = xcat_h[288 + tid - 648];
        }
        __syncthreads();

        // Phase R/S: skip (128x688, KPAD=704 -> KP8=88, S=8)
        mv_partial<128, 88, 8>(wSKIP, skipin_h, partA, tid);
        __syncthreads();
        if (tid < 128) {
            float a = 0.0f;
#pragma unroll
            for (int sl = 0; sl < 8; ++sl) a += partA[sl * 128 + tid];
            float t = tanh_f(a);
            skippre[tid] = t;
            skippre_h[tid] = __float2half(t);
        }
        __syncthreads();

        // Phase T/U: skipglu (128x128)
        mv_partial<128, 16, 8>(wSKIPGLU, skippre_h, partA, tid);
        __syncthreads();
        if (tid < 128) {
            float a = 0.0f;
#pragma unroll
            for (int sl = 0; sl < 8; ++sl) a += partA[sl * 128 + tid];
            skipout_h[tid] = __float2half(skippre[tid] * sigm(a));
        }
        __syncthreads();

        // Phase V: sig partial (40x128, KP8=16, S=8, 320 thr)
        mv_partial<40, 16, 8>(wSIG, skipout_h, partA, tid);
        __syncthreads();
        // Phase W: sig reduce + read old exc
        float keep = (tid < 216) ? exc[tid + 40] : 0.0f;
        if (tid < 40) {
            float a = 0.0f;
#pragma unroll
            for (int sl = 0; sl < 8; ++sl) a += partA[sl * 40 + tid];
            sigraw[tid] = tanh_f(a) * gain;
        }
        __syncthreads();
        // Phase X: exc shift + output
        if (tid < 216) {
            exc[tid] = keep;
        } else if (tid < 256) {
            float sv = sigraw[tid - 216];
            exc[tid] = sv;
            out[(size_t)b * 80000 + (size_t)s * 40 + (tid - 216)] = sv;
        }
        __syncthreads();
    }
}

// ---------------------------------------------------------------------------
extern "C" void kernel_launch(void* const* d_in, const int* in_sizes, int n_in,
                              void* d_out, int out_size, void* d_ws, size_t ws_size,
                              hipStream_t stream) {
    const float* features = (const float*)d_in[0];
    const int*   period   = (const int*)d_in[1];
    const float* pembed   = (const float*)d_in[2];
    const float* fd1_w    = (const float*)d_in[3];
    const float* fconv1_w = (const float*)d_in[4];
    const float* fd2_w    = (const float*)d_in[5];
    const float* cg_w     = (const float*)d_in[6];
    const float* cg_b     = (const float*)d_in[7];
    const float* fwc_w    = (const float*)d_in[8];
    const float* fwc_glu  = (const float*)d_in[9];
    const float* g1_ih    = (const float*)d_in[10];
    const float* g1_hh    = (const float*)d_in[11];
    const float* glu1_w   = (const float*)d_in[12];
    const float* g2_ih    = (const float*)d_in[13];
    const float* g2_hh    = (const float*)d_in[14];
    const float* glu2_w   = (const float*)d_in[15];
    const float* g3_ih    = (const float*)d_in[16];
    const float* g3_hh    = (const float*)d_in[17];
    const float* glu3_w   = (const float*)d_in[18];
    const float* skip_w   = (const float*)d_in[19];
    const float* skip_glu = (const float*)d_in[20];
    const float* sig_w    = (const float*)d_in[21];
    const float* gout_w   = (const float*)d_in[22];
    const float* gout_b   = (const float*)d_in[23];

    float* ws = (float*)d_ws;
    float* out = (float*)d_out;
    __half* wh = (__half*)(ws + OFF_W);

    // ---- pack all recurrent weights to fp16 ([k/8][OUT] uint4 layout) ----
    struct PW { const float* src; size_t off; int out, k, kpad; };
    const PW pws[15] = {
        {fwc_w,    W_FWC,     192, 328, 352}, {fwc_glu, W_FWCGLU, 192, 192, 192},
        {gout_w,   W_GOUT,      4, 192, 192}, {g1_ih,   W_G1IH,   480, 272, 272},
        {g1_hh,    W_G1HH,    480, 160, 160}, {glu1_w,  W_GLU1,   160, 160, 160},
        {g2_ih,    W_G2IH,    384, 240, 240}, {g2_hh,   W_G2HH,   384, 128, 128},
        {glu2_w,   W_GLU2,    128, 128, 128}, {g3_ih,   W_G3IH,   384, 208, 208},
        {g3_hh,    W_G3HH,    384, 128, 128}, {glu3_w,  W_GLU3,   128, 128, 128},
        {skip_w,   W_SKIP,    128, 688, 704}, {skip_glu,W_SKIPGLU,128, 128, 128},
        {sig_w,    W_SIG,      40, 128, 128},
    };
    for (int i = 0; i < 15; ++i) {
        int kp8 = pws[i].kpad / 8;
        int n = pws[i].out * kp8;
        k_pack_h<<<(n + 255) / 256, 256, 0, stream>>>(pws[i].src, wh + pws[i].off,
                                                      pws[i].out, pws[i].k, kp8);
    }

    // ---- frontend ----
    {
        int n = 128 * 502 * 64;
        k_feat<<<(n + 255) / 256, 256, 0, stream>>>(features, period, pembed, fd1_w,
                                                    ws + OFF_X);
    }
    {
        int n = 128 * 500 * 128;
        k_conv<<<(n + 255) / 256, 256, 0, stream>>>(ws + OFF_X, fconv1_w, ws + OFF_Y);
    }
    k_cond<<<128 * 50, 320, 0, stream>>>(ws + OFF_Y, fd2_w, (__half*)(ws + OFF_CONDH));
    {
        int n = 128 * 2000;
        k_gain<<<(n + 255) / 256, 256, 0, stream>>>((const __half*)(ws + OFF_CONDH),
                                                    cg_w, cg_b, ws + OFF_GAIN);
    }

    // ---- recurrence ----
    fargan_main<<<128, 1024, 0, stream>>>(ws, period, gout_b, out);
}